// Round 12
// baseline (611.170 us; speedup 1.0000x reference)
//
#include <hip/hip_runtime.h>

#define VN     5023
#define NBETA  150
#define NBP    152          // padded K: 0..149 betas-dirs, 150 = v_template, 151 = 0
#define NBATCH 1024
#define N3     15069        // V*3
#define BT     16           // batches per block in K3a
#define K1_CHUNK 40

// ---- K0: build sdp[N3][NBP] (cols 0..149 = shapedirs, col 150 = v_template, 151 = 0);
//      also zero JS (first 15*NBP threads). k1_js runs after -> ordering safe.
__global__ void k0_pad(const float* __restrict__ sd, const float* __restrict__ vt,
                       float* __restrict__ sdp, float* __restrict__ JS) {
    int i = blockIdx.x * 256 + threadIdx.x;
    if (i < 15 * NBP) JS[i] = 0.0f;
    if (i >= N3 * NBP) return;
    int row = i / NBP, l = i - row * NBP;
    float val = 0.0f;
    if (l < NBETA) val = sd[row * NBETA + l];
    else if (l == NBETA) val = vt[row];   // v_template folded into column 150
    sdp[i] = val;
}

// ---- K1: JS[j3c][l] += sum_v jr[j,v] * sdp[v*3+c][l]  (col 150 gives Jt for free)
__global__ void k1_js(const float* __restrict__ jr, const float* __restrict__ sdp,
                      float* __restrict__ JS) {
    int j3c = blockIdx.x;              // 0..14
    int j = j3c / 3, c = j3c - 3 * j;
    int l = threadIdx.x;
    if (l >= NBP) return;
    int v0 = blockIdx.y * K1_CHUNK, v1 = min(v0 + K1_CHUNK, VN);
    float acc = 0.0f;
    for (int v = v0; v < v1; ++v)
        acc += jr[j * VN + v] * sdp[(size_t)(v * 3 + c) * NBP + l];
    atomicAdd(&JS[j3c * NBP + l], acc);
}

// ---- rodrigues (matches reference eps semantics) ----
__device__ __forceinline__ void rodrigues3(float x, float y, float z, float* R) {
    float ax = x + 1e-8f, ay = y + 1e-8f, az = z + 1e-8f;
    float ang = sqrtf(ax * ax + ay * ay + az * az);
    float inv = 1.0f / ang;
    float ux = x * inv, uy = y * inv, uz = z * inv;
    float co = cosf(ang), si = sinf(ang), t1 = 1.0f - co;
    float K[9] = {0.f, -uz, uy,  uz, 0.f, -ux,  -uy, ux, 0.f};
    float K2[9];
#pragma unroll
    for (int r = 0; r < 3; r++)
#pragma unroll
        for (int cc = 0; cc < 3; cc++) {
            float a = 0.f;
#pragma unroll
            for (int k = 0; k < 3; k++) a += K[r * 3 + k] * K[k * 3 + cc];
            K2[r * 3 + cc] = a;
        }
#pragma unroll
    for (int i = 0; i < 9; i++) {
        float e = (i == 0 || i == 4 || i == 8) ? 1.f : 0.f;
        R[i] = e + si * K[i] + t1 * K2[i];
    }
}

// ---- K2: per-batch betas (col150=1, col151=0), joints = JS.sB, chain, rel, pf9 ----
__global__ void k2_pose(const float* __restrict__ shp, const float* __restrict__ expr,
                        const float* __restrict__ pose, const float* __restrict__ JS,
                        float* __restrict__ betasF, float* __restrict__ pf9,
                        float* __restrict__ rel) {
    int b = blockIdx.x;
    int tt = threadIdx.x;
    __shared__ float sB[NBP];
    __shared__ float sJ[15];
    for (int l = tt; l < NBP; l += 64) {
        float val = 0.0f;
        if (l < 100) val = shp[b * 100 + l];
        else if (l < 150) val = expr[b * 50 + (l - 100)];
        else if (l == 150) val = 1.0f;   // picks up v_template / Jt columns
        sB[l] = val;
        betasF[b * NBP + l] = val;
    }
    __syncthreads();
    if (tt < 15) {
        float acc = 0.0f;
        const float* row = JS + tt * NBP;
        for (int l = 0; l < NBP; ++l) acc += row[l] * sB[l];
        sJ[tt] = acc;
    }
    __syncthreads();
    if (tt == 0) {
        float p[6];
#pragma unroll
        for (int i = 0; i < 6; i++) p[i] = pose[b * 6 + i];
        float R0[9], RJ[9];
        rodrigues3(p[0], p[1], p[2], R0);
        rodrigues3(p[3], p[4], p[5], RJ);
        float Jm[5][3];
#pragma unroll
        for (int jj = 0; jj < 5; jj++)
#pragma unroll
            for (int cc = 0; cc < 3; cc++) Jm[jj][cc] = sJ[jj * 3 + cc];
        float rj[5][3];
#pragma unroll
        for (int cc = 0; cc < 3; cc++) {
            rj[0][cc] = Jm[0][cc];
            rj[1][cc] = Jm[1][cc] - Jm[0][cc];
            rj[2][cc] = Jm[2][cc] - Jm[1][cc];
            rj[3][cc] = Jm[3][cc] - Jm[1][cc];
            rj[4][cc] = Jm[4][cc] - Jm[1][cc];
        }
        float tw[5][3];
#pragma unroll
        for (int cc = 0; cc < 3; cc++) tw[0][cc] = rj[0][cc];
#pragma unroll
        for (int cc = 0; cc < 3; cc++)
            tw[1][cc] = R0[cc * 3 + 0] * rj[1][0] + R0[cc * 3 + 1] * rj[1][1] + R0[cc * 3 + 2] * rj[1][2] + tw[0][cc];
#pragma unroll
        for (int jj = 2; jj < 5; jj++)
#pragma unroll
            for (int cc = 0; cc < 3; cc++)
                tw[jj][cc] = R0[cc * 3 + 0] * rj[jj][0] + R0[cc * 3 + 1] * rj[jj][1] + R0[cc * 3 + 2] * rj[jj][2] + tw[1][cc];
        float R2w[9];
#pragma unroll
        for (int r = 0; r < 3; r++)
#pragma unroll
            for (int cc = 0; cc < 3; cc++) {
                float a = 0.f;
#pragma unroll
                for (int k = 0; k < 3; k++) a += R0[r * 3 + k] * RJ[k * 3 + cc];
                R2w[r * 3 + cc] = a;
            }
        float* ro = rel + b * 80;
#pragma unroll
        for (int jj = 0; jj < 5; jj++) {
            const float* Rw = (jj == 2) ? R2w : R0;
#pragma unroll
            for (int rr = 0; rr < 3; rr++) {
                ro[jj * 16 + rr * 4 + 0] = Rw[rr * 3 + 0];
                ro[jj * 16 + rr * 4 + 1] = Rw[rr * 3 + 1];
                ro[jj * 16 + rr * 4 + 2] = Rw[rr * 3 + 2];
                float tj = Rw[rr * 3 + 0] * Jm[jj][0] + Rw[rr * 3 + 1] * Jm[jj][1] + Rw[rr * 3 + 2] * Jm[jj][2];
                ro[jj * 16 + rr * 4 + 3] = tw[jj][rr] - tj;
            }
            ro[jj * 16 + 12] = 0.f; ro[jj * 16 + 13] = 0.f; ro[jj * 16 + 14] = 0.f; ro[jj * 16 + 15] = 1.f;
        }
        float* pf = pf9 + b * 12;
#pragma unroll
        for (int e = 0; e < 9; e++) pf[e] = RJ[e] - ((e == 0 || e == 4 || e == 8) ? 1.f : 0.f);
        pf[9] = 0.f; pf[10] = 0.f; pf[11] = 0.f;
    }
}

// ---- K3a: blendshape GEMM + pose blend + vertex LBS (outv ONLY, no T) ----
__global__ void k3a_vert(const float* __restrict__ sdp, const float* __restrict__ pd,
                         const float* __restrict__ lw,
                         const float* __restrict__ betasF, const float* __restrict__ pf9,
                         const float* __restrict__ rel,
                         float* __restrict__ outv) {
    __shared__ float sBet[BT][NBP];   // 9728 B
    __shared__ float sRel[BT][80];    // 5120 B
    __shared__ float sPf[BT][12];     // 768 B

    int tid = threadIdx.x;
    int v = blockIdx.x * 128 + tid;
    bool ok = v < VN;
    int vc = ok ? v : VN - 1;
    int b0 = blockIdx.y * BT;

    for (int i = tid; i < BT * NBP; i += 128) {
        int bb = i / NBP, l = i - bb * NBP;
        sBet[bb][l] = betasF[(size_t)(b0 + bb) * NBP + l];
    }
    for (int i = tid; i < BT * 80; i += 128) {
        int bb = i / 80, e = i - bb * 80;
        sRel[bb][e] = rel[(size_t)(b0 + bb) * 80 + e];
    }
    for (int i = tid; i < BT * 12; i += 128) {
        int bb = i / 12, e = i - bb * 12;
        sPf[bb][e] = pf9[(size_t)(b0 + bb) * 12 + e];
    }

    // epilogue inputs issued early: latency hides under the GEMM FMA stream
    float wj[5], pdv[9][3];
#pragma unroll
    for (int j = 0; j < 5; j++) wj[j] = lw[vc * 5 + j];
#pragma unroll
    for (int k = 0; k < 9; k++)
#pragma unroll
        for (int c = 0; c < 3; c++) pdv[k][c] = pd[(size_t)(9 + k) * N3 + vc * 3 + c];

    __syncthreads();

    float acc[3][BT];
#pragma unroll
    for (int c = 0; c < 3; c++)
#pragma unroll
        for (int bb = 0; bb < BT; bb++) acc[c][bb] = 0.0f;

    const float* srow = sdp + (size_t)vc * 3 * NBP;

#pragma unroll 1
    for (int l0 = 0; l0 < NBP; l0 += 8) {
        const float4 a0  = *(const float4*)(srow + l0);
        const float4 a1  = *(const float4*)(srow + l0 + 4);
        const float4 bq0 = *(const float4*)(srow + NBP + l0);
        const float4 bq1 = *(const float4*)(srow + NBP + l0 + 4);
        const float4 cq0 = *(const float4*)(srow + 2 * NBP + l0);
        const float4 cq1 = *(const float4*)(srow + 2 * NBP + l0 + 4);
        float s0[8] = {a0.x, a0.y, a0.z, a0.w, a1.x, a1.y, a1.z, a1.w};
        float s1[8] = {bq0.x, bq0.y, bq0.z, bq0.w, bq1.x, bq1.y, bq1.z, bq1.w};
        float s2[8] = {cq0.x, cq0.y, cq0.z, cq0.w, cq1.x, cq1.y, cq1.z, cq1.w};
#pragma unroll
        for (int bb = 0; bb < BT; bb++) {
            const float4 be0 = *(const float4*)(&sBet[bb][l0]);
            const float4 be1 = *(const float4*)(&sBet[bb][l0 + 4]);
            float be[8] = {be0.x, be0.y, be0.z, be0.w, be1.x, be1.y, be1.z, be1.w};
#pragma unroll
            for (int k = 0; k < 8; k++) {
                acc[0][bb] += be[k] * s0[k];
                acc[1][bb] += be[k] * s1[k];
                acc[2][bb] += be[k] * s2[k];
            }
        }
    }

    if (!ok) return;

#pragma unroll    // full unroll: acc must stay register-indexed
    for (int bb = 0; bb < BT; bb++) {
        float vp[3];
#pragma unroll
        for (int c = 0; c < 3; c++) {
            float x = acc[c][bb];                     // = v_shaped (template folded in)
#pragma unroll
            for (int k = 0; k < 9; k++) x += sPf[bb][k] * pdv[k][c];
            vp[c] = x;
        }
        float vo0 = 0.f, vo1 = 0.f, vo2 = 0.f;
#pragma unroll
        for (int j = 0; j < 5; j++) {
            const float* r = &sRel[bb][j * 16];
            float w = wj[j];
            vo0 += w * (r[0] * vp[0] + r[1] * vp[1] + r[2]  * vp[2] + r[3]);
            vo1 += w * (r[4] * vp[0] + r[5] * vp[1] + r[6]  * vp[2] + r[7]);
            vo2 += w * (r[8] * vp[0] + r[9] * vp[1] + r[10] * vp[2] + r[11]);
        }
        size_t vbase = (size_t)(b0 + bb) * VN + v;
        float* pv = outv + vbase * 3;
        pv[0] = vo0; pv[1] = vo1; pv[2] = vo2;
    }
}

// ---- K3T: pure streaming T producer: T[b,v,:] = sum_j lw[v,j] * rel[b,j,:] ----
// grid (ceil(VN/1024), NBATCH), block 256. Per thread: 4 vertices, each a full
// 64B line written by 4 consecutive float4 stores (round-10-verified pattern:
// no write amplification). Roofline: 329 MB of writes.
__global__ void k3_T(const float* __restrict__ lw, const float* __restrict__ rel,
                     float* __restrict__ outT) {
    __shared__ float sRel[80];
    int b = blockIdx.y;
    if (threadIdx.x < 80) sRel[threadIdx.x] = rel[b * 80 + threadIdx.x];
    __syncthreads();
    float4 r4[5][4];
#pragma unroll
    for (int j = 0; j < 5; j++)
#pragma unroll
        for (int q = 0; q < 4; q++)
            r4[j][q] = *(const float4*)(&sRel[j * 16 + q * 4]);   // broadcast reads

    size_t tb = (size_t)b * VN;
#pragma unroll
    for (int chunk = 0; chunk < 4; chunk++) {
        int v = blockIdx.x * 1024 + chunk * 256 + threadIdx.x;
        if (v < VN) {
            float w0 = lw[v * 5 + 0], w1 = lw[v * 5 + 1], w2 = lw[v * 5 + 2];
            float w3 = lw[v * 5 + 3], w4 = lw[v * 5 + 4];
            float4* p = (float4*)(outT + (tb + v) * 16);
#pragma unroll
            for (int q = 0; q < 4; q++) {
                float4 t;
                t.x = w0 * r4[0][q].x + w1 * r4[1][q].x + w2 * r4[2][q].x + w3 * r4[3][q].x + w4 * r4[4][q].x;
                t.y = w0 * r4[0][q].y + w1 * r4[1][q].y + w2 * r4[2][q].y + w3 * r4[3][q].y + w4 * r4[4][q].y;
                t.z = w0 * r4[0][q].z + w1 * r4[1][q].z + w2 * r4[2][q].z + w3 * r4[3][q].z + w4 * r4[4][q].z;
                t.w = w0 * r4[0][q].w + w1 * r4[1][q].w + w2 * r4[2][q].w + w3 * r4[3][q].w + w4 * r4[4][q].w;
                p[q] = t;
            }
        }
    }
}

// ---------------- launch ----------------
extern "C" void kernel_launch(void* const* d_in, const int* in_sizes, int n_in,
                              void* d_out, int out_size, void* d_ws, size_t ws_size,
                              hipStream_t stream) {
    const float* shp  = (const float*)d_in[0];  // [1024,100]
    const float* expr = (const float*)d_in[1];  // [1024,50]
    const float* pose = (const float*)d_in[2];  // [1024,6]
    const float* vt   = (const float*)d_in[3];  // [5023,3]
    const float* sd   = (const float*)d_in[4];  // [5023,3,150]
    const float* pd   = (const float*)d_in[5];  // [36,15069]
    const float* jr   = (const float*)d_in[6];  // [5,5023]
    const float* lw   = (const float*)d_in[7];  // [5023,5]

    float* outv = (float*)d_out;
    float* outT = outv + (size_t)NBATCH * VN * 3;

    char* w = (char*)d_ws;
    const size_t SDP_B   = (size_t)N3 * NBP * 4;            // 9,161,952
    const size_t JS_B    = 15 * NBP * 4;                    // 9,120
    const size_t BETAS_B = (size_t)NBATCH * NBP * 4;        // 622,592
    const size_t PF9_B   = (size_t)NBATCH * 12 * 4;         // 49,152
    float* sdp    = (float*)w;
    float* JS     = (float*)(w + SDP_B);
    float* betasF = (float*)(w + SDP_B + JS_B);
    float* pf9    = (float*)(w + SDP_B + JS_B + BETAS_B);
    float* rel    = (float*)(w + SDP_B + JS_B + BETAS_B + PF9_B);

    k0_pad<<<(N3 * NBP + 255) / 256, 256, 0, stream>>>(sd, vt, sdp, JS);
    k1_js<<<dim3(15, (VN + K1_CHUNK - 1) / K1_CHUNK), 192, 0, stream>>>(jr, sdp, JS);
    k2_pose<<<NBATCH, 64, 0, stream>>>(shp, expr, pose, JS, betasF, pf9, rel);
    k3a_vert<<<dim3(40, NBATCH / BT), 128, 0, stream>>>(sdp, pd, lw, betasF, pf9, rel, outv);
    k3_T<<<dim3((VN + 1023) / 1024, NBATCH), 256, 0, stream>>>(lw, rel, outT);
}

// Round 13
// 363.905 us; speedup vs baseline: 1.6795x; 1.6795x over previous
//
#include <hip/hip_runtime.h>

#define VN     5023
#define NBETA  150
#define NBP    152          // padded K: 0..149 betas-dirs, 150 = v_template, 151 = 0
#define NBATCH 1024
#define N3     15069        // V*3
#define BT     16           // batches per block in K3a
#define K1_CHUNK 40

// ---- K0: build sdp[N3][NBP] (cols 0..149 = shapedirs, col 150 = v_template, 151 = 0);
//      also zero JS (first 15*NBP threads). k1_js runs after -> ordering safe.
__global__ void k0_pad(const float* __restrict__ sd, const float* __restrict__ vt,
                       float* __restrict__ sdp, float* __restrict__ JS) {
    int i = blockIdx.x * 256 + threadIdx.x;
    if (i < 15 * NBP) JS[i] = 0.0f;
    if (i >= N3 * NBP) return;
    int row = i / NBP, l = i - row * NBP;
    float val = 0.0f;
    if (l < NBETA) val = sd[row * NBETA + l];
    else if (l == NBETA) val = vt[row];   // v_template folded into column 150
    sdp[i] = val;
}

// ---- K1: JS[j3c][l] += sum_v jr[j,v] * sdp[v*3+c][l]  (col 150 gives Jt for free)
__global__ void k1_js(const float* __restrict__ jr, const float* __restrict__ sdp,
                      float* __restrict__ JS) {
    int j3c = blockIdx.x;              // 0..14
    int j = j3c / 3, c = j3c - 3 * j;
    int l = threadIdx.x;
    if (l >= NBP) return;
    int v0 = blockIdx.y * K1_CHUNK, v1 = min(v0 + K1_CHUNK, VN);
    float acc = 0.0f;
    for (int v = v0; v < v1; ++v)
        acc += jr[j * VN + v] * sdp[(size_t)(v * 3 + c) * NBP + l];
    atomicAdd(&JS[j3c * NBP + l], acc);
}

// ---- rodrigues (matches reference eps semantics) ----
__device__ __forceinline__ void rodrigues3(float x, float y, float z, float* R) {
    float ax = x + 1e-8f, ay = y + 1e-8f, az = z + 1e-8f;
    float ang = sqrtf(ax * ax + ay * ay + az * az);
    float inv = 1.0f / ang;
    float ux = x * inv, uy = y * inv, uz = z * inv;
    float co = cosf(ang), si = sinf(ang), t1 = 1.0f - co;
    float K[9] = {0.f, -uz, uy,  uz, 0.f, -ux,  -uy, ux, 0.f};
    float K2[9];
#pragma unroll
    for (int r = 0; r < 3; r++)
#pragma unroll
        for (int cc = 0; cc < 3; cc++) {
            float a = 0.f;
#pragma unroll
            for (int k = 0; k < 3; k++) a += K[r * 3 + k] * K[k * 3 + cc];
            K2[r * 3 + cc] = a;
        }
#pragma unroll
    for (int i = 0; i < 9; i++) {
        float e = (i == 0 || i == 4 || i == 8) ? 1.f : 0.f;
        R[i] = e + si * K[i] + t1 * K2[i];
    }
}

// ---- K2: per-batch betas (col150=1, col151=0), joints = JS.sB, chain, rel, pf9 ----
__global__ void k2_pose(const float* __restrict__ shp, const float* __restrict__ expr,
                        const float* __restrict__ pose, const float* __restrict__ JS,
                        float* __restrict__ betasF, float* __restrict__ pf9,
                        float* __restrict__ rel) {
    int b = blockIdx.x;
    int tt = threadIdx.x;
    __shared__ float sB[NBP];
    __shared__ float sJ[15];
    for (int l = tt; l < NBP; l += 64) {
        float val = 0.0f;
        if (l < 100) val = shp[b * 100 + l];
        else if (l < 150) val = expr[b * 50 + (l - 100)];
        else if (l == 150) val = 1.0f;   // picks up v_template / Jt columns
        sB[l] = val;
        betasF[b * NBP + l] = val;
    }
    __syncthreads();
    if (tt < 15) {
        float acc = 0.0f;
        const float* row = JS + tt * NBP;
        for (int l = 0; l < NBP; ++l) acc += row[l] * sB[l];
        sJ[tt] = acc;
    }
    __syncthreads();
    if (tt == 0) {
        float p[6];
#pragma unroll
        for (int i = 0; i < 6; i++) p[i] = pose[b * 6 + i];
        float R0[9], RJ[9];
        rodrigues3(p[0], p[1], p[2], R0);
        rodrigues3(p[3], p[4], p[5], RJ);
        float Jm[5][3];
#pragma unroll
        for (int jj = 0; jj < 5; jj++)
#pragma unroll
            for (int cc = 0; cc < 3; cc++) Jm[jj][cc] = sJ[jj * 3 + cc];
        float rj[5][3];
#pragma unroll
        for (int cc = 0; cc < 3; cc++) {
            rj[0][cc] = Jm[0][cc];
            rj[1][cc] = Jm[1][cc] - Jm[0][cc];
            rj[2][cc] = Jm[2][cc] - Jm[1][cc];
            rj[3][cc] = Jm[3][cc] - Jm[1][cc];
            rj[4][cc] = Jm[4][cc] - Jm[1][cc];
        }
        float tw[5][3];
#pragma unroll
        for (int cc = 0; cc < 3; cc++) tw[0][cc] = rj[0][cc];
#pragma unroll
        for (int cc = 0; cc < 3; cc++)
            tw[1][cc] = R0[cc * 3 + 0] * rj[1][0] + R0[cc * 3 + 1] * rj[1][1] + R0[cc * 3 + 2] * rj[1][2] + tw[0][cc];
#pragma unroll
        for (int jj = 2; jj < 5; jj++)
#pragma unroll
            for (int cc = 0; cc < 3; cc++)
                tw[jj][cc] = R0[cc * 3 + 0] * rj[jj][0] + R0[cc * 3 + 1] * rj[jj][1] + R0[cc * 3 + 2] * rj[jj][2] + tw[1][cc];
        float R2w[9];
#pragma unroll
        for (int r = 0; r < 3; r++)
#pragma unroll
            for (int cc = 0; cc < 3; cc++) {
                float a = 0.f;
#pragma unroll
                for (int k = 0; k < 3; k++) a += R0[r * 3 + k] * RJ[k * 3 + cc];
                R2w[r * 3 + cc] = a;
            }
        float* ro = rel + b * 80;
#pragma unroll
        for (int jj = 0; jj < 5; jj++) {
            const float* Rw = (jj == 2) ? R2w : R0;
#pragma unroll
            for (int rr = 0; rr < 3; rr++) {
                ro[jj * 16 + rr * 4 + 0] = Rw[rr * 3 + 0];
                ro[jj * 16 + rr * 4 + 1] = Rw[rr * 3 + 1];
                ro[jj * 16 + rr * 4 + 2] = Rw[rr * 3 + 2];
                float tj = Rw[rr * 3 + 0] * Jm[jj][0] + Rw[rr * 3 + 1] * Jm[jj][1] + Rw[rr * 3 + 2] * Jm[jj][2];
                ro[jj * 16 + rr * 4 + 3] = tw[jj][rr] - tj;
            }
            ro[jj * 16 + 12] = 0.f; ro[jj * 16 + 13] = 0.f; ro[jj * 16 + 14] = 0.f; ro[jj * 16 + 15] = 1.f;
        }
        float* pf = pf9 + b * 12;
#pragma unroll
        for (int e = 0; e < 9; e++) pf[e] = RJ[e] - ((e == 0 || e == 4 || e == 8) ? 1.f : 0.f);
        pf[9] = 0.f; pf[10] = 0.f; pf[11] = 0.f;
    }
}

// ---- K3a: blendshape GEMM + pose blend + vertex LBS (outv ONLY, no T) ----
// CRITICAL: wj/pdv loaded AFTER the GEMM loop. Loading them before (round 12)
// made them live across acc[3][16] -> compiler kept the 64-VGPR bucket and
// SPILLED acc to scratch (FETCH 409MB / WRITE 1GB of pure spill traffic).
__global__ void k3a_vert(const float* __restrict__ sdp, const float* __restrict__ pd,
                         const float* __restrict__ lw,
                         const float* __restrict__ betasF, const float* __restrict__ pf9,
                         const float* __restrict__ rel,
                         float* __restrict__ outv) {
    __shared__ float sBet[BT][NBP];   // 9728 B
    __shared__ float sRel[BT][80];    // 5120 B
    __shared__ float sPf[BT][12];     // 768 B

    int tid = threadIdx.x;
    int v = blockIdx.x * 128 + tid;
    bool ok = v < VN;
    int vc = ok ? v : VN - 1;
    int b0 = blockIdx.y * BT;

    for (int i = tid; i < BT * NBP; i += 128) {
        int bb = i / NBP, l = i - bb * NBP;
        sBet[bb][l] = betasF[(size_t)(b0 + bb) * NBP + l];
    }
    for (int i = tid; i < BT * 80; i += 128) {
        int bb = i / 80, e = i - bb * 80;
        sRel[bb][e] = rel[(size_t)(b0 + bb) * 80 + e];
    }
    for (int i = tid; i < BT * 12; i += 128) {
        int bb = i / 12, e = i - bb * 12;
        sPf[bb][e] = pf9[(size_t)(b0 + bb) * 12 + e];
    }
    __syncthreads();

    float acc[3][BT];
#pragma unroll
    for (int c = 0; c < 3; c++)
#pragma unroll
        for (int bb = 0; bb < BT; bb++) acc[c][bb] = 0.0f;

    const float* srow = sdp + (size_t)vc * 3 * NBP;

#pragma unroll 1
    for (int l0 = 0; l0 < NBP; l0 += 8) {
        const float4 a0  = *(const float4*)(srow + l0);
        const float4 a1  = *(const float4*)(srow + l0 + 4);
        const float4 bq0 = *(const float4*)(srow + NBP + l0);
        const float4 bq1 = *(const float4*)(srow + NBP + l0 + 4);
        const float4 cq0 = *(const float4*)(srow + 2 * NBP + l0);
        const float4 cq1 = *(const float4*)(srow + 2 * NBP + l0 + 4);
        float s0[8] = {a0.x, a0.y, a0.z, a0.w, a1.x, a1.y, a1.z, a1.w};
        float s1[8] = {bq0.x, bq0.y, bq0.z, bq0.w, bq1.x, bq1.y, bq1.z, bq1.w};
        float s2[8] = {cq0.x, cq0.y, cq0.z, cq0.w, cq1.x, cq1.y, cq1.z, cq1.w};
#pragma unroll
        for (int bb = 0; bb < BT; bb++) {
            const float4 be0 = *(const float4*)(&sBet[bb][l0]);
            const float4 be1 = *(const float4*)(&sBet[bb][l0 + 4]);
            float be[8] = {be0.x, be0.y, be0.z, be0.w, be1.x, be1.y, be1.z, be1.w};
#pragma unroll
            for (int k = 0; k < 8; k++) {
                acc[0][bb] += be[k] * s0[k];
                acc[1][bb] += be[k] * s1[k];
                acc[2][bb] += be[k] * s2[k];
            }
        }
    }

    if (!ok) return;

    // epilogue inputs loaded HERE (round-7 placement): acc registers free up as
    // the epilogue consumes them; no spill.
    float wj[5], pdv[9][3];
#pragma unroll
    for (int j = 0; j < 5; j++) wj[j] = lw[v * 5 + j];
#pragma unroll
    for (int k = 0; k < 9; k++)
#pragma unroll
        for (int c = 0; c < 3; c++) pdv[k][c] = pd[(size_t)(9 + k) * N3 + v * 3 + c];

#pragma unroll    // full unroll: acc must stay register-indexed
    for (int bb = 0; bb < BT; bb++) {
        float vp[3];
#pragma unroll
        for (int c = 0; c < 3; c++) {
            float x = acc[c][bb];                     // = v_shaped (template folded in)
#pragma unroll
            for (int k = 0; k < 9; k++) x += sPf[bb][k] * pdv[k][c];
            vp[c] = x;
        }
        float vo0 = 0.f, vo1 = 0.f, vo2 = 0.f;
#pragma unroll
        for (int j = 0; j < 5; j++) {
            const float* r = &sRel[bb][j * 16];
            float w = wj[j];
            vo0 += w * (r[0] * vp[0] + r[1] * vp[1] + r[2]  * vp[2] + r[3]);
            vo1 += w * (r[4] * vp[0] + r[5] * vp[1] + r[6]  * vp[2] + r[7]);
            vo2 += w * (r[8] * vp[0] + r[9] * vp[1] + r[10] * vp[2] + r[11]);
        }
        size_t vbase = (size_t)(b0 + bb) * VN + v;
        float* pv = outv + vbase * 3;
        pv[0] = vo0; pv[1] = vo1; pv[2] = vo2;
    }
}

// ---- K3T: pure streaming T producer: T[b,v,:] = sum_j lw[v,j] * rel[b,j,:] ----
// Measured round 12: absent from top-5 -> <= ~90 us for 329 MB (3.7+ TB/s, near
// write roofline). Unchanged.
__global__ void k3_T(const float* __restrict__ lw, const float* __restrict__ rel,
                     float* __restrict__ outT) {
    __shared__ float sRel[80];
    int b = blockIdx.y;
    if (threadIdx.x < 80) sRel[threadIdx.x] = rel[b * 80 + threadIdx.x];
    __syncthreads();
    float4 r4[5][4];
#pragma unroll
    for (int j = 0; j < 5; j++)
#pragma unroll
        for (int q = 0; q < 4; q++)
            r4[j][q] = *(const float4*)(&sRel[j * 16 + q * 4]);   // broadcast reads

    size_t tb = (size_t)b * VN;
#pragma unroll
    for (int chunk = 0; chunk < 4; chunk++) {
        int v = blockIdx.x * 1024 + chunk * 256 + threadIdx.x;
        if (v < VN) {
            float w0 = lw[v * 5 + 0], w1 = lw[v * 5 + 1], w2 = lw[v * 5 + 2];
            float w3 = lw[v * 5 + 3], w4 = lw[v * 5 + 4];
            float4* p = (float4*)(outT + (tb + v) * 16);
#pragma unroll
            for (int q = 0; q < 4; q++) {
                float4 t;
                t.x = w0 * r4[0][q].x + w1 * r4[1][q].x + w2 * r4[2][q].x + w3 * r4[3][q].x + w4 * r4[4][q].x;
                t.y = w0 * r4[0][q].y + w1 * r4[1][q].y + w2 * r4[2][q].y + w3 * r4[3][q].y + w4 * r4[4][q].y;
                t.z = w0 * r4[0][q].z + w1 * r4[1][q].z + w2 * r4[2][q].z + w3 * r4[3][q].z + w4 * r4[4][q].z;
                t.w = w0 * r4[0][q].w + w1 * r4[1][q].w + w2 * r4[2][q].w + w3 * r4[3][q].w + w4 * r4[4][q].w;
                p[q] = t;
            }
        }
    }
}

// ---------------- launch ----------------
extern "C" void kernel_launch(void* const* d_in, const int* in_sizes, int n_in,
                              void* d_out, int out_size, void* d_ws, size_t ws_size,
                              hipStream_t stream) {
    const float* shp  = (const float*)d_in[0];  // [1024,100]
    const float* expr = (const float*)d_in[1];  // [1024,50]
    const float* pose = (const float*)d_in[2];  // [1024,6]
    const float* vt   = (const float*)d_in[3];  // [5023,3]
    const float* sd   = (const float*)d_in[4];  // [5023,3,150]
    const float* pd   = (const float*)d_in[5];  // [36,15069]
    const float* jr   = (const float*)d_in[6];  // [5,5023]
    const float* lw   = (const float*)d_in[7];  // [5023,5]

    float* outv = (float*)d_out;
    float* outT = outv + (size_t)NBATCH * VN * 3;

    char* w = (char*)d_ws;
    const size_t SDP_B   = (size_t)N3 * NBP * 4;            // 9,161,952
    const size_t JS_B    = 15 * NBP * 4;                    // 9,120
    const size_t BETAS_B = (size_t)NBATCH * NBP * 4;        // 622,592
    const size_t PF9_B   = (size_t)NBATCH * 12 * 4;         // 49,152
    float* sdp    = (float*)w;
    float* JS     = (float*)(w + SDP_B);
    float* betasF = (float*)(w + SDP_B + JS_B);
    float* pf9    = (float*)(w + SDP_B + JS_B + BETAS_B);
    float* rel    = (float*)(w + SDP_B + JS_B + BETAS_B + PF9_B);

    k0_pad<<<(N3 * NBP + 255) / 256, 256, 0, stream>>>(sd, vt, sdp, JS);
    k1_js<<<dim3(15, (VN + K1_CHUNK - 1) / K1_CHUNK), 192, 0, stream>>>(jr, sdp, JS);
    k2_pose<<<NBATCH, 64, 0, stream>>>(shp, expr, pose, JS, betasF, pf9, rel);
    k3a_vert<<<dim3(40, NBATCH / BT), 128, 0, stream>>>(sdp, pd, lw, betasF, pf9, rel, outv);
    k3_T<<<dim3((VN + 1023) / 1024, NBATCH), 256, 0, stream>>>(lw, rel, outT);
}

// Round 14
// 303.552 us; speedup vs baseline: 2.0134x; 1.1988x over previous
//
#include <hip/hip_runtime.h>

#define VN     5023
#define NBETA  150
#define NBP    152          // padded K: 0..149 betas-dirs, 150 = v_template, 151 = 0
#define NBATCH 1024
#define N3     15069        // V*3
#define BT     16           // batches per block in K3a
#define K1_CHUNK 40

// ---- K0: build sdp[N3][NBP] (cols 0..149 = shapedirs, col 150 = v_template, 151 = 0);
//      also zero JS (first 15*NBP threads). k1_js runs after -> ordering safe.
__global__ void k0_pad(const float* __restrict__ sd, const float* __restrict__ vt,
                       float* __restrict__ sdp, float* __restrict__ JS) {
    int i = blockIdx.x * 256 + threadIdx.x;
    if (i < 15 * NBP) JS[i] = 0.0f;
    if (i >= N3 * NBP) return;
    int row = i / NBP, l = i - row * NBP;
    float val = 0.0f;
    if (l < NBETA) val = sd[row * NBETA + l];
    else if (l == NBETA) val = vt[row];   // v_template folded into column 150
    sdp[i] = val;
}

// ---- K1: JS[j3c][l] += sum_v jr[j,v] * sdp[v*3+c][l]  (col 150 gives Jt for free)
__global__ void k1_js(const float* __restrict__ jr, const float* __restrict__ sdp,
                      float* __restrict__ JS) {
    int j3c = blockIdx.x;              // 0..14
    int j = j3c / 3, c = j3c - 3 * j;
    int l = threadIdx.x;
    if (l >= NBP) return;
    int v0 = blockIdx.y * K1_CHUNK, v1 = min(v0 + K1_CHUNK, VN);
    float acc = 0.0f;
    for (int v = v0; v < v1; ++v)
        acc += jr[j * VN + v] * sdp[(size_t)(v * 3 + c) * NBP + l];
    atomicAdd(&JS[j3c * NBP + l], acc);
}

// ---- rodrigues (matches reference eps semantics) ----
__device__ __forceinline__ void rodrigues3(float x, float y, float z, float* R) {
    float ax = x + 1e-8f, ay = y + 1e-8f, az = z + 1e-8f;
    float ang = sqrtf(ax * ax + ay * ay + az * az);
    float inv = 1.0f / ang;
    float ux = x * inv, uy = y * inv, uz = z * inv;
    float co = cosf(ang), si = sinf(ang), t1 = 1.0f - co;
    float K[9] = {0.f, -uz, uy,  uz, 0.f, -ux,  -uy, ux, 0.f};
    float K2[9];
#pragma unroll
    for (int r = 0; r < 3; r++)
#pragma unroll
        for (int cc = 0; cc < 3; cc++) {
            float a = 0.f;
#pragma unroll
            for (int k = 0; k < 3; k++) a += K[r * 3 + k] * K[k * 3 + cc];
            K2[r * 3 + cc] = a;
        }
#pragma unroll
    for (int i = 0; i < 9; i++) {
        float e = (i == 0 || i == 4 || i == 8) ? 1.f : 0.f;
        R[i] = e + si * K[i] + t1 * K2[i];
    }
}

// ---- K2: per-batch betas (col150=1, col151=0), joints = JS.sB, chain, rel, pf9 ----
__global__ void k2_pose(const float* __restrict__ shp, const float* __restrict__ expr,
                        const float* __restrict__ pose, const float* __restrict__ JS,
                        float* __restrict__ betasF, float* __restrict__ pf9,
                        float* __restrict__ rel) {
    int b = blockIdx.x;
    int tt = threadIdx.x;
    __shared__ float sB[NBP];
    __shared__ float sJ[15];
    for (int l = tt; l < NBP; l += 64) {
        float val = 0.0f;
        if (l < 100) val = shp[b * 100 + l];
        else if (l < 150) val = expr[b * 50 + (l - 100)];
        else if (l == 150) val = 1.0f;   // picks up v_template / Jt columns
        sB[l] = val;
        betasF[b * NBP + l] = val;
    }
    __syncthreads();
    if (tt < 15) {
        float acc = 0.0f;
        const float* row = JS + tt * NBP;
        for (int l = 0; l < NBP; ++l) acc += row[l] * sB[l];
        sJ[tt] = acc;
    }
    __syncthreads();
    if (tt == 0) {
        float p[6];
#pragma unroll
        for (int i = 0; i < 6; i++) p[i] = pose[b * 6 + i];
        float R0[9], RJ[9];
        rodrigues3(p[0], p[1], p[2], R0);
        rodrigues3(p[3], p[4], p[5], RJ);
        float Jm[5][3];
#pragma unroll
        for (int jj = 0; jj < 5; jj++)
#pragma unroll
            for (int cc = 0; cc < 3; cc++) Jm[jj][cc] = sJ[jj * 3 + cc];
        float rj[5][3];
#pragma unroll
        for (int cc = 0; cc < 3; cc++) {
            rj[0][cc] = Jm[0][cc];
            rj[1][cc] = Jm[1][cc] - Jm[0][cc];
            rj[2][cc] = Jm[2][cc] - Jm[1][cc];
            rj[3][cc] = Jm[3][cc] - Jm[1][cc];
            rj[4][cc] = Jm[4][cc] - Jm[1][cc];
        }
        float tw[5][3];
#pragma unroll
        for (int cc = 0; cc < 3; cc++) tw[0][cc] = rj[0][cc];
#pragma unroll
        for (int cc = 0; cc < 3; cc++)
            tw[1][cc] = R0[cc * 3 + 0] * rj[1][0] + R0[cc * 3 + 1] * rj[1][1] + R0[cc * 3 + 2] * rj[1][2] + tw[0][cc];
#pragma unroll
        for (int jj = 2; jj < 5; jj++)
#pragma unroll
            for (int cc = 0; cc < 3; cc++)
                tw[jj][cc] = R0[cc * 3 + 0] * rj[jj][0] + R0[cc * 3 + 1] * rj[jj][1] + R0[cc * 3 + 2] * rj[jj][2] + tw[1][cc];
        float R2w[9];
#pragma unroll
        for (int r = 0; r < 3; r++)
#pragma unroll
            for (int cc = 0; cc < 3; cc++) {
                float a = 0.f;
#pragma unroll
                for (int k = 0; k < 3; k++) a += R0[r * 3 + k] * RJ[k * 3 + cc];
                R2w[r * 3 + cc] = a;
            }
        float* ro = rel + b * 80;
#pragma unroll
        for (int jj = 0; jj < 5; jj++) {
            const float* Rw = (jj == 2) ? R2w : R0;
#pragma unroll
            for (int rr = 0; rr < 3; rr++) {
                ro[jj * 16 + rr * 4 + 0] = Rw[rr * 3 + 0];
                ro[jj * 16 + rr * 4 + 1] = Rw[rr * 3 + 1];
                ro[jj * 16 + rr * 4 + 2] = Rw[rr * 3 + 2];
                float tj = Rw[rr * 3 + 0] * Jm[jj][0] + Rw[rr * 3 + 1] * Jm[jj][1] + Rw[rr * 3 + 2] * Jm[jj][2];
                ro[jj * 16 + rr * 4 + 3] = tw[jj][rr] - tj;
            }
            ro[jj * 16 + 12] = 0.f; ro[jj * 16 + 13] = 0.f; ro[jj * 16 + 14] = 0.f; ro[jj * 16 + 15] = 1.f;
        }
        float* pf = pf9 + b * 12;
#pragma unroll
        for (int e = 0; e < 9; e++) pf[e] = RJ[e] - ((e == 0 || e == 4 || e == 8) ? 1.f : 0.f);
        pf[9] = 0.f; pf[10] = 0.f; pf[11] = 0.f;
    }
}

// ---- K3a: blendshape GEMM + pose blend + vertex LBS (outv ONLY, no T) ----
// __launch_bounds__(128, 2): min 2 waves/EU -> VGPR cap 256. Without it the
// allocator pinned 64 VGPRs (8-wave bucket) and spilled ~30 regs PER GEMM
// ITERATION: round-13 counters showed WRITE_SIZE 335 MB for a 62 MB output
// (spill write-back; re-reads hit L2 so FETCH stayed 25 MB). acc[3][16]=48
// regs + pipeline temps need ~100 VGPRs live.
__global__ void __launch_bounds__(128, 2)
k3a_vert(const float* __restrict__ sdp, const float* __restrict__ pd,
         const float* __restrict__ lw,
         const float* __restrict__ betasF, const float* __restrict__ pf9,
         const float* __restrict__ rel,
         float* __restrict__ outv) {
    __shared__ float sBet[BT][NBP];   // 9728 B
    __shared__ float sRel[BT][80];    // 5120 B
    __shared__ float sPf[BT][12];     // 768 B

    int tid = threadIdx.x;
    int v = blockIdx.x * 128 + tid;
    bool ok = v < VN;
    int vc = ok ? v : VN - 1;
    int b0 = blockIdx.y * BT;

    for (int i = tid; i < BT * NBP; i += 128) {
        int bb = i / NBP, l = i - bb * NBP;
        sBet[bb][l] = betasF[(size_t)(b0 + bb) * NBP + l];
    }
    for (int i = tid; i < BT * 80; i += 128) {
        int bb = i / 80, e = i - bb * 80;
        sRel[bb][e] = rel[(size_t)(b0 + bb) * 80 + e];
    }
    for (int i = tid; i < BT * 12; i += 128) {
        int bb = i / 12, e = i - bb * 12;
        sPf[bb][e] = pf9[(size_t)(b0 + bb) * 12 + e];
    }
    __syncthreads();

    float acc[3][BT];
#pragma unroll
    for (int c = 0; c < 3; c++)
#pragma unroll
        for (int bb = 0; bb < BT; bb++) acc[c][bb] = 0.0f;

    const float* srow = sdp + (size_t)vc * 3 * NBP;

#pragma unroll 1
    for (int l0 = 0; l0 < NBP; l0 += 8) {
        const float4 a0  = *(const float4*)(srow + l0);
        const float4 a1  = *(const float4*)(srow + l0 + 4);
        const float4 bq0 = *(const float4*)(srow + NBP + l0);
        const float4 bq1 = *(const float4*)(srow + NBP + l0 + 4);
        const float4 cq0 = *(const float4*)(srow + 2 * NBP + l0);
        const float4 cq1 = *(const float4*)(srow + 2 * NBP + l0 + 4);
        float s0[8] = {a0.x, a0.y, a0.z, a0.w, a1.x, a1.y, a1.z, a1.w};
        float s1[8] = {bq0.x, bq0.y, bq0.z, bq0.w, bq1.x, bq1.y, bq1.z, bq1.w};
        float s2[8] = {cq0.x, cq0.y, cq0.z, cq0.w, cq1.x, cq1.y, cq1.z, cq1.w};
#pragma unroll
        for (int bb = 0; bb < BT; bb++) {
            const float4 be0 = *(const float4*)(&sBet[bb][l0]);
            const float4 be1 = *(const float4*)(&sBet[bb][l0 + 4]);
            float be[8] = {be0.x, be0.y, be0.z, be0.w, be1.x, be1.y, be1.z, be1.w};
#pragma unroll
            for (int k = 0; k < 8; k++) {
                acc[0][bb] += be[k] * s0[k];
                acc[1][bb] += be[k] * s1[k];
                acc[2][bb] += be[k] * s2[k];
            }
        }
    }

    if (!ok) return;

    float wj[5], pdv[9][3];
#pragma unroll
    for (int j = 0; j < 5; j++) wj[j] = lw[v * 5 + j];
#pragma unroll
    for (int k = 0; k < 9; k++)
#pragma unroll
        for (int c = 0; c < 3; c++) pdv[k][c] = pd[(size_t)(9 + k) * N3 + v * 3 + c];

#pragma unroll    // full unroll: acc must stay register-indexed
    for (int bb = 0; bb < BT; bb++) {
        float vp[3];
#pragma unroll
        for (int c = 0; c < 3; c++) {
            float x = acc[c][bb];                     // = v_shaped (template folded in)
#pragma unroll
            for (int k = 0; k < 9; k++) x += sPf[bb][k] * pdv[k][c];
            vp[c] = x;
        }
        float vo0 = 0.f, vo1 = 0.f, vo2 = 0.f;
#pragma unroll
        for (int j = 0; j < 5; j++) {
            const float* r = &sRel[bb][j * 16];
            float w = wj[j];
            vo0 += w * (r[0] * vp[0] + r[1] * vp[1] + r[2]  * vp[2] + r[3]);
            vo1 += w * (r[4] * vp[0] + r[5] * vp[1] + r[6]  * vp[2] + r[7]);
            vo2 += w * (r[8] * vp[0] + r[9] * vp[1] + r[10] * vp[2] + r[11]);
        }
        size_t vbase = (size_t)(b0 + bb) * VN + v;
        float* pv = outv + vbase * 3;
        pv[0] = vo0; pv[1] = vo1; pv[2] = vo2;
    }
}

// ---- K3T: pure streaming T producer: T[b,v,:] = sum_j lw[v,j] * rel[b,j,:] ----
// Measured: ~85 us for 329 MB (3.9 TB/s, near write roofline). Unchanged.
__global__ void k3_T(const float* __restrict__ lw, const float* __restrict__ rel,
                     float* __restrict__ outT) {
    __shared__ float sRel[80];
    int b = blockIdx.y;
    if (threadIdx.x < 80) sRel[threadIdx.x] = rel[b * 80 + threadIdx.x];
    __syncthreads();
    float4 r4[5][4];
#pragma unroll
    for (int j = 0; j < 5; j++)
#pragma unroll
        for (int q = 0; q < 4; q++)
            r4[j][q] = *(const float4*)(&sRel[j * 16 + q * 4]);   // broadcast reads

    size_t tb = (size_t)b * VN;
#pragma unroll
    for (int chunk = 0; chunk < 4; chunk++) {
        int v = blockIdx.x * 1024 + chunk * 256 + threadIdx.x;
        if (v < VN) {
            float w0 = lw[v * 5 + 0], w1 = lw[v * 5 + 1], w2 = lw[v * 5 + 2];
            float w3 = lw[v * 5 + 3], w4 = lw[v * 5 + 4];
            float4* p = (float4*)(outT + (tb + v) * 16);
#pragma unroll
            for (int q = 0; q < 4; q++) {
                float4 t;
                t.x = w0 * r4[0][q].x + w1 * r4[1][q].x + w2 * r4[2][q].x + w3 * r4[3][q].x + w4 * r4[4][q].x;
                t.y = w0 * r4[0][q].y + w1 * r4[1][q].y + w2 * r4[2][q].y + w3 * r4[3][q].y + w4 * r4[4][q].y;
                t.z = w0 * r4[0][q].z + w1 * r4[1][q].z + w2 * r4[2][q].z + w3 * r4[3][q].z + w4 * r4[4][q].z;
                t.w = w0 * r4[0][q].w + w1 * r4[1][q].w + w2 * r4[2][q].w + w3 * r4[3][q].w + w4 * r4[4][q].w;
                p[q] = t;
            }
        }
    }
}

// ---------------- launch ----------------
extern "C" void kernel_launch(void* const* d_in, const int* in_sizes, int n_in,
                              void* d_out, int out_size, void* d_ws, size_t ws_size,
                              hipStream_t stream) {
    const float* shp  = (const float*)d_in[0];  // [1024,100]
    const float* expr = (const float*)d_in[1];  // [1024,50]
    const float* pose = (const float*)d_in[2];  // [1024,6]
    const float* vt   = (const float*)d_in[3];  // [5023,3]
    const float* sd   = (const float*)d_in[4];  // [5023,3,150]
    const float* pd   = (const float*)d_in[5];  // [36,15069]
    const float* jr   = (const float*)d_in[6];  // [5,5023]
    const float* lw   = (const float*)d_in[7];  // [5023,5]

    float* outv = (float*)d_out;
    float* outT = outv + (size_t)NBATCH * VN * 3;

    char* w = (char*)d_ws;
    const size_t SDP_B   = (size_t)N3 * NBP * 4;            // 9,161,952
    const size_t JS_B    = 15 * NBP * 4;                    // 9,120
    const size_t BETAS_B = (size_t)NBATCH * NBP * 4;        // 622,592
    const size_t PF9_B   = (size_t)NBATCH * 12 * 4;         // 49,152
    float* sdp    = (float*)w;
    float* JS     = (float*)(w + SDP_B);
    float* betasF = (float*)(w + SDP_B + JS_B);
    float* pf9    = (float*)(w + SDP_B + JS_B + BETAS_B);
    float* rel    = (float*)(w + SDP_B + JS_B + BETAS_B + PF9_B);

    k0_pad<<<(N3 * NBP + 255) / 256, 256, 0, stream>>>(sd, vt, sdp, JS);
    k1_js<<<dim3(15, (VN + K1_CHUNK - 1) / K1_CHUNK), 192, 0, stream>>>(jr, sdp, JS);
    k2_pose<<<NBATCH, 64, 0, stream>>>(shp, expr, pose, JS, betasF, pf9, rel);
    k3a_vert<<<dim3(40, NBATCH / BT), 128, 0, stream>>>(sdp, pd, lw, betasF, pf9, rel, outv);
    k3_T<<<dim3((VN + 1023) / 1024, NBATCH), 256, 0, stream>>>(lw, rel, outT);
}

// Round 15
// 245.111 us; speedup vs baseline: 2.4934x; 1.2384x over previous
//
#include <hip/hip_runtime.h>

#define VN     5023
#define NBETA  150
#define NBP    152          // padded K: 0..149 betas-dirs, 150 = v_template, 151 = 0
#define NBATCH 1024
#define N3     15069        // V*3
#define BT     16           // batches per block in K3
#define K1_CHUNK 40

// ---- K0: build sdp[N3][NBP] (cols 0..149 = shapedirs, col 150 = v_template, 151 = 0);
//      also zero JS (first 15*NBP threads). k1_js runs after -> ordering safe.
__global__ void k0_pad(const float* __restrict__ sd, const float* __restrict__ vt,
                       float* __restrict__ sdp, float* __restrict__ JS) {
    int i = blockIdx.x * 256 + threadIdx.x;
    if (i < 15 * NBP) JS[i] = 0.0f;
    if (i >= N3 * NBP) return;
    int row = i / NBP, l = i - row * NBP;
    float val = 0.0f;
    if (l < NBETA) val = sd[row * NBETA + l];
    else if (l == NBETA) val = vt[row];   // v_template folded into column 150
    sdp[i] = val;
}

// ---- K1: JS[j3c][l] += sum_v jr[j,v] * sdp[v*3+c][l]  (col 150 gives Jt for free)
__global__ void k1_js(const float* __restrict__ jr, const float* __restrict__ sdp,
                      float* __restrict__ JS) {
    int j3c = blockIdx.x;              // 0..14
    int j = j3c / 3, c = j3c - 3 * j;
    int l = threadIdx.x;
    if (l >= NBP) return;
    int v0 = blockIdx.y * K1_CHUNK, v1 = min(v0 + K1_CHUNK, VN);
    float acc = 0.0f;
    for (int v = v0; v < v1; ++v)
        acc += jr[j * VN + v] * sdp[(size_t)(v * 3 + c) * NBP + l];
    atomicAdd(&JS[j3c * NBP + l], acc);
}

// ---- rodrigues (matches reference eps semantics) ----
__device__ __forceinline__ void rodrigues3(float x, float y, float z, float* R) {
    float ax = x + 1e-8f, ay = y + 1e-8f, az = z + 1e-8f;
    float ang = sqrtf(ax * ax + ay * ay + az * az);
    float inv = 1.0f / ang;
    float ux = x * inv, uy = y * inv, uz = z * inv;
    float co = cosf(ang), si = sinf(ang), t1 = 1.0f - co;
    float K[9] = {0.f, -uz, uy,  uz, 0.f, -ux,  -uy, ux, 0.f};
    float K2[9];
#pragma unroll
    for (int r = 0; r < 3; r++)
#pragma unroll
        for (int cc = 0; cc < 3; cc++) {
            float a = 0.f;
#pragma unroll
            for (int k = 0; k < 3; k++) a += K[r * 3 + k] * K[k * 3 + cc];
            K2[r * 3 + cc] = a;
        }
#pragma unroll
    for (int i = 0; i < 9; i++) {
        float e = (i == 0 || i == 4 || i == 8) ? 1.f : 0.f;
        R[i] = e + si * K[i] + t1 * K2[i];
    }
}

// ---- K2: per-batch betas (col150=1, col151=0), joints = JS.sB, chain, rel, pf9 ----
__global__ void k2_pose(const float* __restrict__ shp, const float* __restrict__ expr,
                        const float* __restrict__ pose, const float* __restrict__ JS,
                        float* __restrict__ betasF, float* __restrict__ pf9,
                        float* __restrict__ rel) {
    int b = blockIdx.x;
    int tt = threadIdx.x;
    __shared__ float sB[NBP];
    __shared__ float sJ[15];
    for (int l = tt; l < NBP; l += 64) {
        float val = 0.0f;
        if (l < 100) val = shp[b * 100 + l];
        else if (l < 150) val = expr[b * 50 + (l - 100)];
        else if (l == 150) val = 1.0f;   // picks up v_template / Jt columns
        sB[l] = val;
        betasF[b * NBP + l] = val;
    }
    __syncthreads();
    if (tt < 15) {
        float acc = 0.0f;
        const float* row = JS + tt * NBP;
        for (int l = 0; l < NBP; ++l) acc += row[l] * sB[l];
        sJ[tt] = acc;
    }
    __syncthreads();
    if (tt == 0) {
        float p[6];
#pragma unroll
        for (int i = 0; i < 6; i++) p[i] = pose[b * 6 + i];
        float R0[9], RJ[9];
        rodrigues3(p[0], p[1], p[2], R0);
        rodrigues3(p[3], p[4], p[5], RJ);
        float Jm[5][3];
#pragma unroll
        for (int jj = 0; jj < 5; jj++)
#pragma unroll
            for (int cc = 0; cc < 3; cc++) Jm[jj][cc] = sJ[jj * 3 + cc];
        float rj[5][3];
#pragma unroll
        for (int cc = 0; cc < 3; cc++) {
            rj[0][cc] = Jm[0][cc];
            rj[1][cc] = Jm[1][cc] - Jm[0][cc];
            rj[2][cc] = Jm[2][cc] - Jm[1][cc];
            rj[3][cc] = Jm[3][cc] - Jm[1][cc];
            rj[4][cc] = Jm[4][cc] - Jm[1][cc];
        }
        float tw[5][3];
#pragma unroll
        for (int cc = 0; cc < 3; cc++) tw[0][cc] = rj[0][cc];
#pragma unroll
        for (int cc = 0; cc < 3; cc++)
            tw[1][cc] = R0[cc * 3 + 0] * rj[1][0] + R0[cc * 3 + 1] * rj[1][1] + R0[cc * 3 + 2] * rj[1][2] + tw[0][cc];
#pragma unroll
        for (int jj = 2; jj < 5; jj++)
#pragma unroll
            for (int cc = 0; cc < 3; cc++)
                tw[jj][cc] = R0[cc * 3 + 0] * rj[jj][0] + R0[cc * 3 + 1] * rj[jj][1] + R0[cc * 3 + 2] * rj[jj][2] + tw[1][cc];
        float R2w[9];
#pragma unroll
        for (int r = 0; r < 3; r++)
#pragma unroll
            for (int cc = 0; cc < 3; cc++) {
                float a = 0.f;
#pragma unroll
                for (int k = 0; k < 3; k++) a += R0[r * 3 + k] * RJ[k * 3 + cc];
                R2w[r * 3 + cc] = a;
            }
        float* ro = rel + b * 80;
#pragma unroll
        for (int jj = 0; jj < 5; jj++) {
            const float* Rw = (jj == 2) ? R2w : R0;
#pragma unroll
            for (int rr = 0; rr < 3; rr++) {
                ro[jj * 16 + rr * 4 + 0] = Rw[rr * 3 + 0];
                ro[jj * 16 + rr * 4 + 1] = Rw[rr * 3 + 1];
                ro[jj * 16 + rr * 4 + 2] = Rw[rr * 3 + 2];
                float tj = Rw[rr * 3 + 0] * Jm[jj][0] + Rw[rr * 3 + 1] * Jm[jj][1] + Rw[rr * 3 + 2] * Jm[jj][2];
                ro[jj * 16 + rr * 4 + 3] = tw[jj][rr] - tj;
            }
            ro[jj * 16 + 12] = 0.f; ro[jj * 16 + 13] = 0.f; ro[jj * 16 + 14] = 0.f; ro[jj * 16 + 15] = 1.f;
        }
        float* pf = pf9 + b * 12;
#pragma unroll
        for (int e = 0; e < 9; e++) pf[e] = RJ[e] - ((e == 0 || e == 4 || e == 8) ? 1.f : 0.f);
        pf[9] = 0.f; pf[10] = 0.f; pf[11] = 0.f;
    }
}

// ---- K3: fused blendshape GEMM + pose blend + LBS + T output ----
// launch_bounds(128,2): VGPR cap 256 -> no spill (round 13/14: without it the
// allocator pinned 64 VGPRs and spilled acc every GEMM iteration, 273 MB of
// scratch write-back). T fused back in: its 330 MB write stream drains
// concurrently with the GEMM compute (k3a alone left write BW idle; separate
// k3_T paid its HBM time serially). Per-thread T row stores measured at
// mandatory WRITE_SIZE (round 10).
__global__ void __launch_bounds__(128, 2)
k3_main(const float* __restrict__ sdp, const float* __restrict__ pd,
        const float* __restrict__ lw,
        const float* __restrict__ betasF, const float* __restrict__ pf9,
        const float* __restrict__ rel,
        float* __restrict__ outv, float* __restrict__ outT) {
    __shared__ float sBet[BT][NBP];   // 9728 B
    __shared__ float sRel[BT][80];    // 5120 B
    __shared__ float sPf[BT][12];     // 768 B

    int tid = threadIdx.x;
    int v = blockIdx.x * 128 + tid;
    bool ok = v < VN;
    int vc = ok ? v : VN - 1;
    int b0 = blockIdx.y * BT;

    for (int i = tid; i < BT * NBP; i += 128) {
        int bb = i / NBP, l = i - bb * NBP;
        sBet[bb][l] = betasF[(size_t)(b0 + bb) * NBP + l];
    }
    for (int i = tid; i < BT * 80; i += 128) {
        int bb = i / 80, e = i - bb * 80;
        sRel[bb][e] = rel[(size_t)(b0 + bb) * 80 + e];
    }
    for (int i = tid; i < BT * 12; i += 128) {
        int bb = i / 12, e = i - bb * 12;
        sPf[bb][e] = pf9[(size_t)(b0 + bb) * 12 + e];
    }
    __syncthreads();

    float acc[3][BT];
#pragma unroll
    for (int c = 0; c < 3; c++)
#pragma unroll
        for (int bb = 0; bb < BT; bb++) acc[c][bb] = 0.0f;

    const float* srow = sdp + (size_t)vc * 3 * NBP;

#pragma unroll 1
    for (int l0 = 0; l0 < NBP; l0 += 8) {
        const float4 a0  = *(const float4*)(srow + l0);
        const float4 a1  = *(const float4*)(srow + l0 + 4);
        const float4 bq0 = *(const float4*)(srow + NBP + l0);
        const float4 bq1 = *(const float4*)(srow + NBP + l0 + 4);
        const float4 cq0 = *(const float4*)(srow + 2 * NBP + l0);
        const float4 cq1 = *(const float4*)(srow + 2 * NBP + l0 + 4);
        float s0[8] = {a0.x, a0.y, a0.z, a0.w, a1.x, a1.y, a1.z, a1.w};
        float s1[8] = {bq0.x, bq0.y, bq0.z, bq0.w, bq1.x, bq1.y, bq1.z, bq1.w};
        float s2[8] = {cq0.x, cq0.y, cq0.z, cq0.w, cq1.x, cq1.y, cq1.z, cq1.w};
#pragma unroll
        for (int bb = 0; bb < BT; bb++) {
            const float4 be0 = *(const float4*)(&sBet[bb][l0]);
            const float4 be1 = *(const float4*)(&sBet[bb][l0 + 4]);
            float be[8] = {be0.x, be0.y, be0.z, be0.w, be1.x, be1.y, be1.z, be1.w};
#pragma unroll
            for (int k = 0; k < 8; k++) {
                acc[0][bb] += be[k] * s0[k];
                acc[1][bb] += be[k] * s1[k];
                acc[2][bb] += be[k] * s2[k];
            }
        }
    }

    if (!ok) return;

    // epilogue inputs loaded AFTER the GEMM (spill-safe placement, round 13)
    float wj[5], pdv[9][3];
#pragma unroll
    for (int j = 0; j < 5; j++) wj[j] = lw[v * 5 + j];
#pragma unroll
    for (int k = 0; k < 9; k++)
#pragma unroll
        for (int c = 0; c < 3; c++) pdv[k][c] = pd[(size_t)(9 + k) * N3 + v * 3 + c];

#pragma unroll    // full unroll: acc must stay register-indexed
    for (int bb = 0; bb < BT; bb++) {
        int b = b0 + bb;
        float vp[3];
#pragma unroll
        for (int c = 0; c < 3; c++) {
            float x = acc[c][bb];                     // = v_shaped (template folded in)
#pragma unroll
            for (int k = 0; k < 9; k++) x += sPf[bb][k] * pdv[k][c];
            vp[c] = x;
        }
        float T[16];
#pragma unroll
        for (int e = 0; e < 16; e++) T[e] = 0.0f;
#pragma unroll
        for (int j = 0; j < 5; j++) {
            float w = wj[j];
            const float4* rj4 = (const float4*)(&sRel[bb][j * 16]);
            float4 r0 = rj4[0], r1 = rj4[1], r2 = rj4[2], r3 = rj4[3];
            T[0]  += w * r0.x;  T[1]  += w * r0.y;  T[2]  += w * r0.z;  T[3]  += w * r0.w;
            T[4]  += w * r1.x;  T[5]  += w * r1.y;  T[6]  += w * r1.z;  T[7]  += w * r1.w;
            T[8]  += w * r2.x;  T[9]  += w * r2.y;  T[10] += w * r2.z;  T[11] += w * r2.w;
            T[12] += w * r3.x;  T[13] += w * r3.y;  T[14] += w * r3.z;  T[15] += w * r3.w;
        }
        float vo[3];
#pragma unroll
        for (int rr = 0; rr < 3; rr++)
            vo[rr] = T[rr * 4 + 0] * vp[0] + T[rr * 4 + 1] * vp[1] + T[rr * 4 + 2] * vp[2] + T[rr * 4 + 3];

        size_t vbase = (size_t)b * VN + v;
        float* pv = outv + vbase * 3;
        pv[0] = vo[0];
        pv[1] = vo[1];
        pv[2] = vo[2];
        float4* pT = (float4*)(outT + vbase * 16);
        pT[0] = make_float4(T[0],  T[1],  T[2],  T[3]);
        pT[1] = make_float4(T[4],  T[5],  T[6],  T[7]);
        pT[2] = make_float4(T[8],  T[9],  T[10], T[11]);
        pT[3] = make_float4(T[12], T[13], T[14], T[15]);
    }
}

// ---------------- launch ----------------
extern "C" void kernel_launch(void* const* d_in, const int* in_sizes, int n_in,
                              void* d_out, int out_size, void* d_ws, size_t ws_size,
                              hipStream_t stream) {
    const float* shp  = (const float*)d_in[0];  // [1024,100]
    const float* expr = (const float*)d_in[1];  // [1024,50]
    const float* pose = (const float*)d_in[2];  // [1024,6]
    const float* vt   = (const float*)d_in[3];  // [5023,3]
    const float* sd   = (const float*)d_in[4];  // [5023,3,150]
    const float* pd   = (const float*)d_in[5];  // [36,15069]
    const float* jr   = (const float*)d_in[6];  // [5,5023]
    const float* lw   = (const float*)d_in[7];  // [5023,5]

    float* outv = (float*)d_out;
    float* outT = outv + (size_t)NBATCH * VN * 3;

    char* w = (char*)d_ws;
    const size_t SDP_B   = (size_t)N3 * NBP * 4;            // 9,161,952
    const size_t JS_B    = 15 * NBP * 4;                    // 9,120
    const size_t BETAS_B = (size_t)NBATCH * NBP * 4;        // 622,592
    const size_t PF9_B   = (size_t)NBATCH * 12 * 4;         // 49,152
    float* sdp    = (float*)w;
    float* JS     = (float*)(w + SDP_B);
    float* betasF = (float*)(w + SDP_B + JS_B);
    float* pf9    = (float*)(w + SDP_B + JS_B + BETAS_B);
    float* rel    = (float*)(w + SDP_B + JS_B + BETAS_B + PF9_B);

    k0_pad<<<(N3 * NBP + 255) / 256, 256, 0, stream>>>(sd, vt, sdp, JS);
    k1_js<<<dim3(15, (VN + K1_CHUNK - 1) / K1_CHUNK), 192, 0, stream>>>(jr, sdp, JS);
    k2_pose<<<NBATCH, 64, 0, stream>>>(shp, expr, pose, JS, betasF, pf9, rel);
    k3_main<<<dim3(40, NBATCH / BT), 128, 0, stream>>>(sdp, pd, lw, betasF, pf9, rel, outv, outT);
}

// Round 16
// 239.036 us; speedup vs baseline: 2.5568x; 1.0254x over previous
//
#include <hip/hip_runtime.h>

#define VN     5023
#define NBETA  150
#define NBP    152          // padded K: 0..149 betas-dirs, 150 = v_template, 151 = 0
#define NL4    38           // NBP/4: float4-grouped K index
#define VP     5024         // vertex-padded stride for transposed layout
#define NBATCH 1024
#define N3     15069        // V*3
#define BT     16           // batches per block in K3

// ---- K0: build TRANSPOSED panel sdpT4[c][l4][v] (float4 = K-values 4l4..4l4+3).
// Vertex index is contiguous -> k3's GEMM loads are fully coalesced
// (64 lanes x 16B = 1KB/inst = 16 lines, vs 64 lines with the row-major layout).
__global__ void k0_t4(const float* __restrict__ sd, const float* __restrict__ vt,
                      float4* __restrict__ sdpT4) {
    int i = blockIdx.x * 256 + threadIdx.x;
    if (i >= 3 * NL4 * VP) return;
    int c   = i / (NL4 * VP);
    int rem = i - c * (NL4 * VP);
    int l4  = rem / VP;
    int v   = rem - l4 * VP;
    float4 out = make_float4(0.f, 0.f, 0.f, 0.f);
    if (v < VN) {
        int row = v * 3 + c;
        float vals[4];
#pragma unroll
        for (int q = 0; q < 4; q++) {
            int ll = l4 * 4 + q;
            vals[q] = (ll < NBETA) ? sd[row * NBETA + ll]
                     : ((ll == NBETA) ? vt[row] : 0.f);
        }
        out = make_float4(vals[0], vals[1], vals[2], vals[3]);
    }
    sdpT4[i] = out;   // consecutive i -> consecutive v: coalesced write
}

// ---- K1: JS[j3c][4*l4+q] = sum_v jr[j,v] * sdpT4[c][l4][v].q
// One block per (j3c, l4): coalesced float4 reads, direct store (no atomics).
__global__ void k1_t4(const float* __restrict__ jr, const float4* __restrict__ sdpT4,
                      float* __restrict__ JS) {
    int j3c = blockIdx.x, l4 = blockIdx.y;
    int j = j3c / 3, c = j3c - 3 * j;
    int t = threadIdx.x;
    const float4* col = sdpT4 + (size_t)(c * NL4 + l4) * VP;
    float4 acc = make_float4(0.f, 0.f, 0.f, 0.f);
    for (int v = t; v < VN; v += 256) {
        float w = jr[j * VN + v];
        float4 s = col[v];
        acc.x += w * s.x; acc.y += w * s.y; acc.z += w * s.z; acc.w += w * s.w;
    }
    __shared__ float4 red[256];
    red[t] = acc; __syncthreads();
    for (int s = 128; s > 0; s >>= 1) {
        if (t < s) {
            red[t].x += red[t + s].x; red[t].y += red[t + s].y;
            red[t].z += red[t + s].z; red[t].w += red[t + s].w;
        }
        __syncthreads();
    }
    if (t == 0) {
        JS[j3c * NBP + l4 * 4 + 0] = red[0].x;
        JS[j3c * NBP + l4 * 4 + 1] = red[0].y;
        JS[j3c * NBP + l4 * 4 + 2] = red[0].z;
        JS[j3c * NBP + l4 * 4 + 3] = red[0].w;
    }
}

// ---- rodrigues (matches reference eps semantics) ----
__device__ __forceinline__ void rodrigues3(float x, float y, float z, float* R) {
    float ax = x + 1e-8f, ay = y + 1e-8f, az = z + 1e-8f;
    float ang = sqrtf(ax * ax + ay * ay + az * az);
    float inv = 1.0f / ang;
    float ux = x * inv, uy = y * inv, uz = z * inv;
    float co = cosf(ang), si = sinf(ang), t1 = 1.0f - co;
    float K[9] = {0.f, -uz, uy,  uz, 0.f, -ux,  -uy, ux, 0.f};
    float K2[9];
#pragma unroll
    for (int r = 0; r < 3; r++)
#pragma unroll
        for (int cc = 0; cc < 3; cc++) {
            float a = 0.f;
#pragma unroll
            for (int k = 0; k < 3; k++) a += K[r * 3 + k] * K[k * 3 + cc];
            K2[r * 3 + cc] = a;
        }
#pragma unroll
    for (int i = 0; i < 9; i++) {
        float e = (i == 0 || i == 4 || i == 8) ? 1.f : 0.f;
        R[i] = e + si * K[i] + t1 * K2[i];
    }
}

// ---- K2: per-batch betas (col150=1, col151=0), joints = JS.sB, chain, rel, pf9 ----
__global__ void k2_pose(const float* __restrict__ shp, const float* __restrict__ expr,
                        const float* __restrict__ pose, const float* __restrict__ JS,
                        float* __restrict__ betasF, float* __restrict__ pf9,
                        float* __restrict__ rel) {
    int b = blockIdx.x;
    int tt = threadIdx.x;
    __shared__ float sB[NBP];
    __shared__ float sJ[15];
    for (int l = tt; l < NBP; l += 64) {
        float val = 0.0f;
        if (l < 100) val = shp[b * 100 + l];
        else if (l < 150) val = expr[b * 50 + (l - 100)];
        else if (l == 150) val = 1.0f;   // picks up v_template / Jt columns
        sB[l] = val;
        betasF[b * NBP + l] = val;
    }
    __syncthreads();
    if (tt < 15) {
        float acc = 0.0f;
        const float* row = JS + tt * NBP;
        for (int l = 0; l < NBP; ++l) acc += row[l] * sB[l];
        sJ[tt] = acc;
    }
    __syncthreads();
    if (tt == 0) {
        float p[6];
#pragma unroll
        for (int i = 0; i < 6; i++) p[i] = pose[b * 6 + i];
        float R0[9], RJ[9];
        rodrigues3(p[0], p[1], p[2], R0);
        rodrigues3(p[3], p[4], p[5], RJ);
        float Jm[5][3];
#pragma unroll
        for (int jj = 0; jj < 5; jj++)
#pragma unroll
            for (int cc = 0; cc < 3; cc++) Jm[jj][cc] = sJ[jj * 3 + cc];
        float rj[5][3];
#pragma unroll
        for (int cc = 0; cc < 3; cc++) {
            rj[0][cc] = Jm[0][cc];
            rj[1][cc] = Jm[1][cc] - Jm[0][cc];
            rj[2][cc] = Jm[2][cc] - Jm[1][cc];
            rj[3][cc] = Jm[3][cc] - Jm[1][cc];
            rj[4][cc] = Jm[4][cc] - Jm[1][cc];
        }
        float tw[5][3];
#pragma unroll
        for (int cc = 0; cc < 3; cc++) tw[0][cc] = rj[0][cc];
#pragma unroll
        for (int cc = 0; cc < 3; cc++)
            tw[1][cc] = R0[cc * 3 + 0] * rj[1][0] + R0[cc * 3 + 1] * rj[1][1] + R0[cc * 3 + 2] * rj[1][2] + tw[0][cc];
#pragma unroll
        for (int jj = 2; jj < 5; jj++)
#pragma unroll
            for (int cc = 0; cc < 3; cc++)
                tw[jj][cc] = R0[cc * 3 + 0] * rj[jj][0] + R0[cc * 3 + 1] * rj[jj][1] + R0[cc * 3 + 2] * rj[jj][2] + tw[1][cc];
        float R2w[9];
#pragma unroll
        for (int r = 0; r < 3; r++)
#pragma unroll
            for (int cc = 0; cc < 3; cc++) {
                float a = 0.f;
#pragma unroll
                for (int k = 0; k < 3; k++) a += R0[r * 3 + k] * RJ[k * 3 + cc];
                R2w[r * 3 + cc] = a;
            }
        float* ro = rel + b * 80;
#pragma unroll
        for (int jj = 0; jj < 5; jj++) {
            const float* Rw = (jj == 2) ? R2w : R0;
#pragma unroll
            for (int rr = 0; rr < 3; rr++) {
                ro[jj * 16 + rr * 4 + 0] = Rw[rr * 3 + 0];
                ro[jj * 16 + rr * 4 + 1] = Rw[rr * 3 + 1];
                ro[jj * 16 + rr * 4 + 2] = Rw[rr * 3 + 2];
                float tj = Rw[rr * 3 + 0] * Jm[jj][0] + Rw[rr * 3 + 1] * Jm[jj][1] + Rw[rr * 3 + 2] * Jm[jj][2];
                ro[jj * 16 + rr * 4 + 3] = tw[jj][rr] - tj;
            }
            ro[jj * 16 + 12] = 0.f; ro[jj * 16 + 13] = 0.f; ro[jj * 16 + 14] = 0.f; ro[jj * 16 + 15] = 1.f;
        }
        float* pf = pf9 + b * 12;
#pragma unroll
        for (int e = 0; e < 9; e++) pf[e] = RJ[e] - ((e == 0 || e == 4 || e == 8) ? 1.f : 0.f);
        pf[9] = 0.f; pf[10] = 0.f; pf[11] = 0.f;
    }
}

// ---- K3: fused blendshape GEMM + pose blend + LBS + T output ----
// launch_bounds(128,2): spill-free (round 13/14). GEMM loads now hit the
// TRANSPOSED panel: lane-stride 16B -> 16 lines/inst instead of 64 (round 15's
// 226us was TA line-scatter-bound: 384 lines/wave-iter, all L1-miss).
__global__ void __launch_bounds__(128, 2)
k3_main(const float4* __restrict__ sdpT4, const float* __restrict__ pd,
        const float* __restrict__ lw,
        const float* __restrict__ betasF, const float* __restrict__ pf9,
        const float* __restrict__ rel,
        float* __restrict__ outv, float* __restrict__ outT) {
    __shared__ float sBet[BT][NBP];   // 9728 B
    __shared__ float sRel[BT][80];    // 5120 B
    __shared__ float sPf[BT][12];     // 768 B

    int tid = threadIdx.x;
    int v = blockIdx.x * 128 + tid;
    bool ok = v < VN;
    int vc = ok ? v : VN - 1;
    int b0 = blockIdx.y * BT;

    for (int i = tid; i < BT * NBP; i += 128) {
        int bb = i / NBP, l = i - bb * NBP;
        sBet[bb][l] = betasF[(size_t)(b0 + bb) * NBP + l];
    }
    for (int i = tid; i < BT * 80; i += 128) {
        int bb = i / 80, e = i - bb * 80;
        sRel[bb][e] = rel[(size_t)(b0 + bb) * 80 + e];
    }
    for (int i = tid; i < BT * 12; i += 128) {
        int bb = i / 12, e = i - bb * 12;
        sPf[bb][e] = pf9[(size_t)(b0 + bb) * 12 + e];
    }
    __syncthreads();

    float acc[3][BT];
#pragma unroll
    for (int c = 0; c < 3; c++)
#pragma unroll
        for (int bb = 0; bb < BT; bb++) acc[c][bb] = 0.0f;

    const float4* sp = sdpT4 + vc;   // + (c*NL4 + l4)*VP walks K; lane walks v

#pragma unroll 1
    for (int l0 = 0; l0 < NBP; l0 += 8) {
        int i0 = l0 >> 2;
        const float4 a0 = sp[(size_t)(0 * NL4 + i0) * VP];
        const float4 a1 = sp[(size_t)(0 * NL4 + i0 + 1) * VP];
        const float4 b0q = sp[(size_t)(1 * NL4 + i0) * VP];
        const float4 b1q = sp[(size_t)(1 * NL4 + i0 + 1) * VP];
        const float4 c0q = sp[(size_t)(2 * NL4 + i0) * VP];
        const float4 c1q = sp[(size_t)(2 * NL4 + i0 + 1) * VP];
        float s0[8] = {a0.x, a0.y, a0.z, a0.w, a1.x, a1.y, a1.z, a1.w};
        float s1[8] = {b0q.x, b0q.y, b0q.z, b0q.w, b1q.x, b1q.y, b1q.z, b1q.w};
        float s2[8] = {c0q.x, c0q.y, c0q.z, c0q.w, c1q.x, c1q.y, c1q.z, c1q.w};
#pragma unroll
        for (int bb = 0; bb < BT; bb++) {
            const float4 be0 = *(const float4*)(&sBet[bb][l0]);
            const float4 be1 = *(const float4*)(&sBet[bb][l0 + 4]);
            float be[8] = {be0.x, be0.y, be0.z, be0.w, be1.x, be1.y, be1.z, be1.w};
#pragma unroll
            for (int k = 0; k < 8; k++) {
                acc[0][bb] += be[k] * s0[k];
                acc[1][bb] += be[k] * s1[k];
                acc[2][bb] += be[k] * s2[k];
            }
        }
    }

    if (!ok) return;

    // epilogue inputs loaded AFTER the GEMM (spill-safe placement, round 13)
    float wj[5], pdv[9][3];
#pragma unroll
    for (int j = 0; j < 5; j++) wj[j] = lw[v * 5 + j];
#pragma unroll
    for (int k = 0; k < 9; k++)
#pragma unroll
        for (int c = 0; c < 3; c++) pdv[k][c] = pd[(size_t)(9 + k) * N3 + v * 3 + c];

#pragma unroll    // full unroll: acc must stay register-indexed
    for (int bb = 0; bb < BT; bb++) {
        int b = b0 + bb;
        float vp[3];
#pragma unroll
        for (int c = 0; c < 3; c++) {
            float x = acc[c][bb];                     // = v_shaped (template folded in)
#pragma unroll
            for (int k = 0; k < 9; k++) x += sPf[bb][k] * pdv[k][c];
            vp[c] = x;
        }
        float T[16];
#pragma unroll
        for (int e = 0; e < 16; e++) T[e] = 0.0f;
#pragma unroll
        for (int j = 0; j < 5; j++) {
            float w = wj[j];
            const float4* rj4 = (const float4*)(&sRel[bb][j * 16]);
            float4 r0 = rj4[0], r1 = rj4[1], r2 = rj4[2], r3 = rj4[3];
            T[0]  += w * r0.x;  T[1]  += w * r0.y;  T[2]  += w * r0.z;  T[3]  += w * r0.w;
            T[4]  += w * r1.x;  T[5]  += w * r1.y;  T[6]  += w * r1.z;  T[7]  += w * r1.w;
            T[8]  += w * r2.x;  T[9]  += w * r2.y;  T[10] += w * r2.z;  T[11] += w * r2.w;
            T[12] += w * r3.x;  T[13] += w * r3.y;  T[14] += w * r3.z;  T[15] += w * r3.w;
        }
        float vo[3];
#pragma unroll
        for (int rr = 0; rr < 3; rr++)
            vo[rr] = T[rr * 4 + 0] * vp[0] + T[rr * 4 + 1] * vp[1] + T[rr * 4 + 2] * vp[2] + T[rr * 4 + 3];

        size_t vbase = (size_t)b * VN + v;
        float* pv = outv + vbase * 3;
        pv[0] = vo[0];
        pv[1] = vo[1];
        pv[2] = vo[2];
        float4* pT = (float4*)(outT + vbase * 16);
        pT[0] = make_float4(T[0],  T[1],  T[2],  T[3]);
        pT[1] = make_float4(T[4],  T[5],  T[6],  T[7]);
        pT[2] = make_float4(T[8],  T[9],  T[10], T[11]);
        pT[3] = make_float4(T[12], T[13], T[14], T[15]);
    }
}

// ---------------- launch ----------------
extern "C" void kernel_launch(void* const* d_in, const int* in_sizes, int n_in,
                              void* d_out, int out_size, void* d_ws, size_t ws_size,
                              hipStream_t stream) {
    const float* shp  = (const float*)d_in[0];  // [1024,100]
    const float* expr = (const float*)d_in[1];  // [1024,50]
    const float* pose = (const float*)d_in[2];  // [1024,6]
    const float* vt   = (const float*)d_in[3];  // [5023,3]
    const float* sd   = (const float*)d_in[4];  // [5023,3,150]
    const float* pd   = (const float*)d_in[5];  // [36,15069]
    const float* jr   = (const float*)d_in[6];  // [5,5023]
    const float* lw   = (const float*)d_in[7];  // [5023,5]

    float* outv = (float*)d_out;
    float* outT = outv + (size_t)NBATCH * VN * 3;

    char* w = (char*)d_ws;
    const size_t SDPT_B  = (size_t)3 * NL4 * VP * 16;       // 9,163,776
    const size_t JS_B    = 15 * NBP * 4;                    // 9,120
    const size_t BETAS_B = (size_t)NBATCH * NBP * 4;        // 622,592
    const size_t PF9_B   = (size_t)NBATCH * 12 * 4;         // 49,152
    float4* sdpT4 = (float4*)w;
    float* JS     = (float*)(w + SDPT_B);
    float* betasF = (float*)(w + SDPT_B + JS_B);
    float* pf9    = (float*)(w + SDPT_B + JS_B + BETAS_B);
    float* rel    = (float*)(w + SDPT_B + JS_B + BETAS_B + PF9_B);

    k0_t4<<<(3 * NL4 * VP + 255) / 256, 256, 0, stream>>>(sd, vt, sdpT4);
    k1_t4<<<dim3(15, NL4), 256, 0, stream>>>(jr, sdpT4, JS);
    k2_pose<<<NBATCH, 64, 0, stream>>>(shp, expr, pose, JS, betasF, pf9, rel);
    k3_main<<<dim3(40, NBATCH / BT), 128, 0, stream>>>(sdpT4, pd, lw, betasF, pf9, rel, outv, outT);
}

// Round 17
// 238.936 us; speedup vs baseline: 2.5579x; 1.0004x over previous
//
#include <hip/hip_runtime.h>

#define VN     5023
#define NBETA  150
#define NBP    152          // padded K: 0..149 betas-dirs, 150 = v_template, 151 = 0
#define NL4    38           // NBP/4: float4-grouped K index
#define VP     5024         // vertex-padded stride for transposed layout
#define NBATCH 1024
#define N3     15069        // V*3
#define BT     16           // batches per block in K3

// ---- K0: build TRANSPOSED panel sdpT4[c][l4][v] (float4 = K-values 4l4..4l4+3). ----
__global__ void k0_t4(const float* __restrict__ sd, const float* __restrict__ vt,
                      float4* __restrict__ sdpT4) {
    int i = blockIdx.x * 256 + threadIdx.x;
    if (i >= 3 * NL4 * VP) return;
    int c   = i / (NL4 * VP);
    int rem = i - c * (NL4 * VP);
    int l4  = rem / VP;
    int v   = rem - l4 * VP;
    float4 out = make_float4(0.f, 0.f, 0.f, 0.f);
    if (v < VN) {
        int row = v * 3 + c;
        float vals[4];
#pragma unroll
        for (int q = 0; q < 4; q++) {
            int ll = l4 * 4 + q;
            vals[q] = (ll < NBETA) ? sd[row * NBETA + ll]
                     : ((ll == NBETA) ? vt[row] : 0.f);
        }
        out = make_float4(vals[0], vals[1], vals[2], vals[3]);
    }
    sdpT4[i] = out;   // consecutive i -> consecutive v: coalesced write
}

// ---- K1: JS[j3c][4*l4+q] = sum_v jr[j,v] * sdpT4[c][l4][v].q ----
__global__ void k1_t4(const float* __restrict__ jr, const float4* __restrict__ sdpT4,
                      float* __restrict__ JS) {
    int j3c = blockIdx.x, l4 = blockIdx.y;
    int j = j3c / 3, c = j3c - 3 * j;
    int t = threadIdx.x;
    const float4* col = sdpT4 + (size_t)(c * NL4 + l4) * VP;
    float4 acc = make_float4(0.f, 0.f, 0.f, 0.f);
    for (int v = t; v < VN; v += 256) {
        float w = jr[j * VN + v];
        float4 s = col[v];
        acc.x += w * s.x; acc.y += w * s.y; acc.z += w * s.z; acc.w += w * s.w;
    }
    __shared__ float4 red[256];
    red[t] = acc; __syncthreads();
    for (int s = 128; s > 0; s >>= 1) {
        if (t < s) {
            red[t].x += red[t + s].x; red[t].y += red[t + s].y;
            red[t].z += red[t + s].z; red[t].w += red[t + s].w;
        }
        __syncthreads();
    }
    if (t == 0) {
        JS[j3c * NBP + l4 * 4 + 0] = red[0].x;
        JS[j3c * NBP + l4 * 4 + 1] = red[0].y;
        JS[j3c * NBP + l4 * 4 + 2] = red[0].z;
        JS[j3c * NBP + l4 * 4 + 3] = red[0].w;
    }
}

// ---- rodrigues (matches reference eps semantics) ----
__device__ __forceinline__ void rodrigues3(float x, float y, float z, float* R) {
    float ax = x + 1e-8f, ay = y + 1e-8f, az = z + 1e-8f;
    float ang = sqrtf(ax * ax + ay * ay + az * az);
    float inv = 1.0f / ang;
    float ux = x * inv, uy = y * inv, uz = z * inv;
    float co = cosf(ang), si = sinf(ang), t1 = 1.0f - co;
    float K[9] = {0.f, -uz, uy,  uz, 0.f, -ux,  -uy, ux, 0.f};
    float K2[9];
#pragma unroll
    for (int r = 0; r < 3; r++)
#pragma unroll
        for (int cc = 0; cc < 3; cc++) {
            float a = 0.f;
#pragma unroll
            for (int k = 0; k < 3; k++) a += K[r * 3 + k] * K[k * 3 + cc];
            K2[r * 3 + cc] = a;
        }
#pragma unroll
    for (int i = 0; i < 9; i++) {
        float e = (i == 0 || i == 4 || i == 8) ? 1.f : 0.f;
        R[i] = e + si * K[i] + t1 * K2[i];
    }
}

// ---- K2: per-batch betas (col150=1, col151=0), joints = JS.sB, chain, rel, pf9 ----
__global__ void k2_pose(const float* __restrict__ shp, const float* __restrict__ expr,
                        const float* __restrict__ pose, const float* __restrict__ JS,
                        float* __restrict__ betasF, float* __restrict__ pf9,
                        float* __restrict__ rel) {
    int b = blockIdx.x;
    int tt = threadIdx.x;
    __shared__ float sB[NBP];
    __shared__ float sJ[15];
    for (int l = tt; l < NBP; l += 64) {
        float val = 0.0f;
        if (l < 100) val = shp[b * 100 + l];
        else if (l < 150) val = expr[b * 50 + (l - 100)];
        else if (l == 150) val = 1.0f;   // picks up v_template / Jt columns
        sB[l] = val;
        betasF[b * NBP + l] = val;
    }
    __syncthreads();
    if (tt < 15) {
        float acc = 0.0f;
        const float* row = JS + tt * NBP;
        for (int l = 0; l < NBP; ++l) acc += row[l] * sB[l];
        sJ[tt] = acc;
    }
    __syncthreads();
    if (tt == 0) {
        float p[6];
#pragma unroll
        for (int i = 0; i < 6; i++) p[i] = pose[b * 6 + i];
        float R0[9], RJ[9];
        rodrigues3(p[0], p[1], p[2], R0);
        rodrigues3(p[3], p[4], p[5], RJ);
        float Jm[5][3];
#pragma unroll
        for (int jj = 0; jj < 5; jj++)
#pragma unroll
            for (int cc = 0; cc < 3; cc++) Jm[jj][cc] = sJ[jj * 3 + cc];
        float rj[5][3];
#pragma unroll
        for (int cc = 0; cc < 3; cc++) {
            rj[0][cc] = Jm[0][cc];
            rj[1][cc] = Jm[1][cc] - Jm[0][cc];
            rj[2][cc] = Jm[2][cc] - Jm[1][cc];
            rj[3][cc] = Jm[3][cc] - Jm[1][cc];
            rj[4][cc] = Jm[4][cc] - Jm[1][cc];
        }
        float tw[5][3];
#pragma unroll
        for (int cc = 0; cc < 3; cc++) tw[0][cc] = rj[0][cc];
#pragma unroll
        for (int cc = 0; cc < 3; cc++)
            tw[1][cc] = R0[cc * 3 + 0] * rj[1][0] + R0[cc * 3 + 1] * rj[1][1] + R0[cc * 3 + 2] * rj[1][2] + tw[0][cc];
#pragma unroll
        for (int jj = 2; jj < 5; jj++)
#pragma unroll
            for (int cc = 0; cc < 3; cc++)
                tw[jj][cc] = R0[cc * 3 + 0] * rj[jj][0] + R0[cc * 3 + 1] * rj[jj][1] + R0[cc * 3 + 2] * rj[jj][2] + tw[1][cc];
        float R2w[9];
#pragma unroll
        for (int r = 0; r < 3; r++)
#pragma unroll
            for (int cc = 0; cc < 3; cc++) {
                float a = 0.f;
#pragma unroll
                for (int k = 0; k < 3; k++) a += R0[r * 3 + k] * RJ[k * 3 + cc];
                R2w[r * 3 + cc] = a;
            }
        float* ro = rel + b * 80;
#pragma unroll
        for (int jj = 0; jj < 5; jj++) {
            const float* Rw = (jj == 2) ? R2w : R0;
#pragma unroll
            for (int rr = 0; rr < 3; rr++) {
                ro[jj * 16 + rr * 4 + 0] = Rw[rr * 3 + 0];
                ro[jj * 16 + rr * 4 + 1] = Rw[rr * 3 + 1];
                ro[jj * 16 + rr * 4 + 2] = Rw[rr * 3 + 2];
                float tj = Rw[rr * 3 + 0] * Jm[jj][0] + Rw[rr * 3 + 1] * Jm[jj][1] + Rw[rr * 3 + 2] * Jm[jj][2];
                ro[jj * 16 + rr * 4 + 3] = tw[jj][rr] - tj;
            }
            ro[jj * 16 + 12] = 0.f; ro[jj * 16 + 13] = 0.f; ro[jj * 16 + 14] = 0.f; ro[jj * 16 + 15] = 1.f;
        }
        float* pf = pf9 + b * 12;
#pragma unroll
        for (int e = 0; e < 9; e++) pf[e] = RJ[e] - ((e == 0 || e == 4 || e == 8) ? 1.f : 0.f);
        pf[9] = 0.f; pf[10] = 0.f; pf[11] = 0.f;
    }
}

// ---- K3: fused GEMM + pose blend + LBS + T, ZERO LDS ----
// Rounds 6-16 were LDS-pipe-bound: 608 broadcast ds_read_b128/wave in the GEMM,
// one LDS unit per CU shared by 4 SIMDs -> 2x oversubscribed -> VALUBusy ~33%.
// All betas/rel/pf9 addresses are wave-uniform -> read from GLOBAL with uniform
// addressing: compiler emits s_load into SGPRs (scalar cache), freeing the LDS
// pipe entirely. FMAs use the SGPR operand directly (1 SGPR/VOP allowed).
__global__ void __launch_bounds__(128, 2)
k3_main(const float4* __restrict__ sdpT4, const float* __restrict__ pd,
        const float* __restrict__ lw,
        const float* __restrict__ betasF, const float* __restrict__ pf9,
        const float* __restrict__ rel,
        float* __restrict__ outv, float* __restrict__ outT) {
    int tid = threadIdx.x;
    int v = blockIdx.x * 128 + tid;
    bool ok = v < VN;
    int vc = ok ? v : VN - 1;
    int b0 = blockIdx.y * BT;

    float acc[3][BT];
#pragma unroll
    for (int c = 0; c < 3; c++)
#pragma unroll
        for (int bb = 0; bb < BT; bb++) acc[c][bb] = 0.0f;

    const float4* sp = sdpT4 + vc;   // + (c*NL4 + l4)*VP walks K; lane walks v

#pragma unroll 1
    for (int l0 = 0; l0 < NBP; l0 += 8) {
        int i0 = l0 >> 2;
        const float4 a0  = sp[(size_t)(0 * NL4 + i0) * VP];
        const float4 a1  = sp[(size_t)(0 * NL4 + i0 + 1) * VP];
        const float4 b0q = sp[(size_t)(1 * NL4 + i0) * VP];
        const float4 b1q = sp[(size_t)(1 * NL4 + i0 + 1) * VP];
        const float4 c0q = sp[(size_t)(2 * NL4 + i0) * VP];
        const float4 c1q = sp[(size_t)(2 * NL4 + i0 + 1) * VP];
        float s0[8] = {a0.x, a0.y, a0.z, a0.w, a1.x, a1.y, a1.z, a1.w};
        float s1[8] = {b0q.x, b0q.y, b0q.z, b0q.w, b1q.x, b1q.y, b1q.z, b1q.w};
        float s2[8] = {c0q.x, c0q.y, c0q.z, c0q.w, c1q.x, c1q.y, c1q.z, c1q.w};
#pragma unroll
        for (int bb = 0; bb < BT; bb++) {
            // uniform address -> scalar loads (SGPR), not LDS/vector path
            const float* brow = betasF + (size_t)(b0 + bb) * NBP + l0;
            const float4 be0 = *(const float4*)(brow);
            const float4 be1 = *(const float4*)(brow + 4);
            float be[8] = {be0.x, be0.y, be0.z, be0.w, be1.x, be1.y, be1.z, be1.w};
#pragma unroll
            for (int k = 0; k < 8; k++) {
                acc[0][bb] += be[k] * s0[k];
                acc[1][bb] += be[k] * s1[k];
                acc[2][bb] += be[k] * s2[k];
            }
        }
    }

    if (!ok) return;

    // per-lane epilogue inputs (vector loads), spill-safe placement (round 13)
    float wj[5], pdv[9][3];
#pragma unroll
    for (int j = 0; j < 5; j++) wj[j] = lw[v * 5 + j];
#pragma unroll
    for (int k = 0; k < 9; k++)
#pragma unroll
        for (int c = 0; c < 3; c++) pdv[k][c] = pd[(size_t)(9 + k) * N3 + v * 3 + c];

#pragma unroll    // full unroll: acc must stay register-indexed
    for (int bb = 0; bb < BT; bb++) {
        int b = b0 + bb;
        const float* pf = pf9 + b * 12;   // uniform -> scalar loads
        const float* rb = rel + b * 80;   // uniform -> scalar loads
        float vp[3];
#pragma unroll
        for (int c = 0; c < 3; c++) {
            float x = acc[c][bb];                     // = v_shaped (template folded in)
#pragma unroll
            for (int k = 0; k < 9; k++) x += pf[k] * pdv[k][c];
            vp[c] = x;
        }
        float T[16];
#pragma unroll
        for (int e = 0; e < 16; e++) T[e] = 0.0f;
#pragma unroll
        for (int j = 0; j < 5; j++) {
            float w = wj[j];
            const float4 r0 = *(const float4*)(rb + j * 16 + 0);
            const float4 r1 = *(const float4*)(rb + j * 16 + 4);
            const float4 r2 = *(const float4*)(rb + j * 16 + 8);
            const float4 r3 = *(const float4*)(rb + j * 16 + 12);
            T[0]  += w * r0.x;  T[1]  += w * r0.y;  T[2]  += w * r0.z;  T[3]  += w * r0.w;
            T[4]  += w * r1.x;  T[5]  += w * r1.y;  T[6]  += w * r1.z;  T[7]  += w * r1.w;
            T[8]  += w * r2.x;  T[9]  += w * r2.y;  T[10] += w * r2.z;  T[11] += w * r2.w;
            T[12] += w * r3.x;  T[13] += w * r3.y;  T[14] += w * r3.z;  T[15] += w * r3.w;
        }
        float vo[3];
#pragma unroll
        for (int rr = 0; rr < 3; rr++)
            vo[rr] = T[rr * 4 + 0] * vp[0] + T[rr * 4 + 1] * vp[1] + T[rr * 4 + 2] * vp[2] + T[rr * 4 + 3];

        size_t vbase = (size_t)b * VN + v;
        float* pv = outv + vbase * 3;
        pv[0] = vo[0];
        pv[1] = vo[1];
        pv[2] = vo[2];
        float4* pT = (float4*)(outT + vbase * 16);
        pT[0] = make_float4(T[0],  T[1],  T[2],  T[3]);
        pT[1] = make_float4(T[4],  T[5],  T[6],  T[7]);
        pT[2] = make_float4(T[8],  T[9],  T[10], T[11]);
        pT[3] = make_float4(T[12], T[13], T[14], T[15]);
    }
}

// ---------------- launch ----------------
extern "C" void kernel_launch(void* const* d_in, const int* in_sizes, int n_in,
                              void* d_out, int out_size, void* d_ws, size_t ws_size,
                              hipStream_t stream) {
    const float* shp  = (const float*)d_in[0];  // [1024,100]
    const float* expr = (const float*)d_in[1];  // [1024,50]
    const float* pose = (const float*)d_in[2];  // [1024,6]
    const float* vt   = (const float*)d_in[3];  // [5023,3]
    const float* sd   = (const float*)d_in[4];  // [5023,3,150]
    const float* pd   = (const float*)d_in[5];  // [36,15069]
    const float* jr   = (const float*)d_in[6];  // [5,5023]
    const float* lw   = (const float*)d_in[7];  // [5023,5]

    float* outv = (float*)d_out;
    float* outT = outv + (size_t)NBATCH * VN * 3;

    char* w = (char*)d_ws;
    const size_t SDPT_B  = (size_t)3 * NL4 * VP * 16;       // 9,163,776
    const size_t JS_B    = 15 * NBP * 4;                    // 9,120
    const size_t BETAS_B = (size_t)NBATCH * NBP * 4;        // 622,592
    const size_t PF9_B   = (size_t)NBATCH * 12 * 4;         // 49,152
    float4* sdpT4 = (float4*)w;
    float* JS     = (float*)(w + SDPT_B);
    float* betasF = (float*)(w + SDPT_B + JS_B);
    float* pf9    = (float*)(w + SDPT_B + JS_B + BETAS_B);
    float* rel    = (float*)(w + SDPT_B + JS_B + BETAS_B + PF9_B);

    k0_t4<<<(3 * NL4 * VP + 255) / 256, 256, 0, stream>>>(sd, vt, sdpT4);
    k1_t4<<<dim3(15, NL4), 256, 0, stream>>>(jr, sdpT4, JS);
    k2_pose<<<NBATCH, 64, 0, stream>>>(shp, expr, pose, JS, betasF, pf9, rel);
    k3_main<<<dim3(40, NBATCH / BT), 128, 0, stream>>>(sdpT4, pd, lw, betasF, pf9, rel, outv, outT);
}

// Round 18
// 238.770 us; speedup vs baseline: 2.5597x; 1.0007x over previous
//
#include <hip/hip_runtime.h>

#define VN     5023
#define NBETA  150
#define NBP    152          // padded K: 0..149 betas-dirs, 150 = v_template, 151 = 0
#define NL4    38           // NBP/4: float4-grouped K index
#define VP     5024         // vertex-padded stride for transposed layout
#define NBATCH 1024
#define N3     15069        // V*3
#define BT     16           // batches per block in K3

// ---- K0: build TRANSPOSED panel sdpT4[c][l4][v] (float4 = K-values 4l4..4l4+3). ----
__global__ void k0_t4(const float* __restrict__ sd, const float* __restrict__ vt,
                      float4* __restrict__ sdpT4) {
    int i = blockIdx.x * 256 + threadIdx.x;
    if (i >= 3 * NL4 * VP) return;
    int c   = i / (NL4 * VP);
    int rem = i - c * (NL4 * VP);
    int l4  = rem / VP;
    int v   = rem - l4 * VP;
    float4 out = make_float4(0.f, 0.f, 0.f, 0.f);
    if (v < VN) {
        int row = v * 3 + c;
        float vals[4];
#pragma unroll
        for (int q = 0; q < 4; q++) {
            int ll = l4 * 4 + q;
            vals[q] = (ll < NBETA) ? sd[row * NBETA + ll]
                     : ((ll == NBETA) ? vt[row] : 0.f);
        }
        out = make_float4(vals[0], vals[1], vals[2], vals[3]);
    }
    sdpT4[i] = out;   // consecutive i -> consecutive v: coalesced write
}

// ---- K1: JS[j3c][4*l4+q] = sum_v jr[j,v] * sdpT4[c][l4][v].q ----
__global__ void k1_t4(const float* __restrict__ jr, const float4* __restrict__ sdpT4,
                      float* __restrict__ JS) {
    int j3c = blockIdx.x, l4 = blockIdx.y;
    int j = j3c / 3, c = j3c - 3 * j;
    int t = threadIdx.x;
    const float4* col = sdpT4 + (size_t)(c * NL4 + l4) * VP;
    float4 acc = make_float4(0.f, 0.f, 0.f, 0.f);
    for (int v = t; v < VN; v += 256) {
        float w = jr[j * VN + v];
        float4 s = col[v];
        acc.x += w * s.x; acc.y += w * s.y; acc.z += w * s.z; acc.w += w * s.w;
    }
    __shared__ float4 red[256];
    red[t] = acc; __syncthreads();
    for (int s = 128; s > 0; s >>= 1) {
        if (t < s) {
            red[t].x += red[t + s].x; red[t].y += red[t + s].y;
            red[t].z += red[t + s].z; red[t].w += red[t + s].w;
        }
        __syncthreads();
    }
    if (t == 0) {
        JS[j3c * NBP + l4 * 4 + 0] = red[0].x;
        JS[j3c * NBP + l4 * 4 + 1] = red[0].y;
        JS[j3c * NBP + l4 * 4 + 2] = red[0].z;
        JS[j3c * NBP + l4 * 4 + 3] = red[0].w;
    }
}

// ---- rodrigues (matches reference eps semantics) ----
__device__ __forceinline__ void rodrigues3(float x, float y, float z, float* R) {
    float ax = x + 1e-8f, ay = y + 1e-8f, az = z + 1e-8f;
    float ang = sqrtf(ax * ax + ay * ay + az * az);
    float inv = 1.0f / ang;
    float ux = x * inv, uy = y * inv, uz = z * inv;
    float co = cosf(ang), si = sinf(ang), t1 = 1.0f - co;
    float K[9] = {0.f, -uz, uy,  uz, 0.f, -ux,  -uy, ux, 0.f};
    float K2[9];
#pragma unroll
    for (int r = 0; r < 3; r++)
#pragma unroll
        for (int cc = 0; cc < 3; cc++) {
            float a = 0.f;
#pragma unroll
            for (int k = 0; k < 3; k++) a += K[r * 3 + k] * K[k * 3 + cc];
            K2[r * 3 + cc] = a;
        }
#pragma unroll
    for (int i = 0; i < 9; i++) {
        float e = (i == 0 || i == 4 || i == 8) ? 1.f : 0.f;
        R[i] = e + si * K[i] + t1 * K2[i];
    }
}

// ---- K2: per-batch betas (col150=1, col151=0), joints = JS.sB, chain, rel, pf9 ----
__global__ void k2_pose(const float* __restrict__ shp, const float* __restrict__ expr,
                        const float* __restrict__ pose, const float* __restrict__ JS,
                        float* __restrict__ betasF, float* __restrict__ pf9,
                        float* __restrict__ rel) {
    int b = blockIdx.x;
    int tt = threadIdx.x;
    __shared__ float sB[NBP];
    __shared__ float sJ[15];
    for (int l = tt; l < NBP; l += 64) {
        float val = 0.0f;
        if (l < 100) val = shp[b * 100 + l];
        else if (l < 150) val = expr[b * 50 + (l - 100)];
        else if (l == 150) val = 1.0f;   // picks up v_template / Jt columns
        sB[l] = val;
        betasF[b * NBP + l] = val;
    }
    __syncthreads();
    if (tt < 15) {
        float acc = 0.0f;
        const float* row = JS + tt * NBP;
        for (int l = 0; l < NBP; ++l) acc += row[l] * sB[l];
        sJ[tt] = acc;
    }
    __syncthreads();
    if (tt == 0) {
        float p[6];
#pragma unroll
        for (int i = 0; i < 6; i++) p[i] = pose[b * 6 + i];
        float R0[9], RJ[9];
        rodrigues3(p[0], p[1], p[2], R0);
        rodrigues3(p[3], p[4], p[5], RJ);
        float Jm[5][3];
#pragma unroll
        for (int jj = 0; jj < 5; jj++)
#pragma unroll
            for (int cc = 0; cc < 3; cc++) Jm[jj][cc] = sJ[jj * 3 + cc];
        float rj[5][3];
#pragma unroll
        for (int cc = 0; cc < 3; cc++) {
            rj[0][cc] = Jm[0][cc];
            rj[1][cc] = Jm[1][cc] - Jm[0][cc];
            rj[2][cc] = Jm[2][cc] - Jm[1][cc];
            rj[3][cc] = Jm[3][cc] - Jm[1][cc];
            rj[4][cc] = Jm[4][cc] - Jm[1][cc];
        }
        float tw[5][3];
#pragma unroll
        for (int cc = 0; cc < 3; cc++) tw[0][cc] = rj[0][cc];
#pragma unroll
        for (int cc = 0; cc < 3; cc++)
            tw[1][cc] = R0[cc * 3 + 0] * rj[1][0] + R0[cc * 3 + 1] * rj[1][1] + R0[cc * 3 + 2] * rj[1][2] + tw[0][cc];
#pragma unroll
        for (int jj = 2; jj < 5; jj++)
#pragma unroll
            for (int cc = 0; cc < 3; cc++)
                tw[jj][cc] = R0[cc * 3 + 0] * rj[jj][0] + R0[cc * 3 + 1] * rj[jj][1] + R0[cc * 3 + 2] * rj[jj][2] + tw[1][cc];
        float R2w[9];
#pragma unroll
        for (int r = 0; r < 3; r++)
#pragma unroll
            for (int cc = 0; cc < 3; cc++) {
                float a = 0.f;
#pragma unroll
                for (int k = 0; k < 3; k++) a += R0[r * 3 + k] * RJ[k * 3 + cc];
                R2w[r * 3 + cc] = a;
            }
        float* ro = rel + b * 80;
#pragma unroll
        for (int jj = 0; jj < 5; jj++) {
            const float* Rw = (jj == 2) ? R2w : R0;
#pragma unroll
            for (int rr = 0; rr < 3; rr++) {
                ro[jj * 16 + rr * 4 + 0] = Rw[rr * 3 + 0];
                ro[jj * 16 + rr * 4 + 1] = Rw[rr * 3 + 1];
                ro[jj * 16 + rr * 4 + 2] = Rw[rr * 3 + 2];
                float tj = Rw[rr * 3 + 0] * Jm[jj][0] + Rw[rr * 3 + 1] * Jm[jj][1] + Rw[rr * 3 + 2] * Jm[jj][2];
                ro[jj * 16 + rr * 4 + 3] = tw[jj][rr] - tj;
            }
            ro[jj * 16 + 12] = 0.f; ro[jj * 16 + 13] = 0.f; ro[jj * 16 + 14] = 0.f; ro[jj * 16 + 15] = 1.f;
        }
        float* pf = pf9 + b * 12;
#pragma unroll
        for (int e = 0; e < 9; e++) pf[e] = RJ[e] - ((e == 0 || e == 4 || e == 8) ? 1.f : 0.f);
        pf[9] = 0.f; pf[10] = 0.f; pf[11] = 0.f;
    }
}

// ---- K3: fused GEMM + pose blend + LBS + T, no LDS, SW-PIPELINED sdp loads ----
// Round-7's prefetch was a silent no-op because the 64-VGPR allocator spilled
// the staging registers. With launch_bounds(128,2) (cap 256) the double-buffer
// is real: iter i+1's 6 loads issue BEFORE iter i's 768-cycle FMA block, hiding
// the ~200-600cy L2 latency that round-17's budget identifies as the ~150us
// stall (VALUBusy 33% == FMA-floor/dur).
__global__ void __launch_bounds__(128, 2)
k3_main(const float4* __restrict__ sdpT4, const float* __restrict__ pd,
        const float* __restrict__ lw,
        const float* __restrict__ betasF, const float* __restrict__ pf9,
        const float* __restrict__ rel,
        float* __restrict__ outv, float* __restrict__ outT) {
    int tid = threadIdx.x;
    int v = blockIdx.x * 128 + tid;
    bool ok = v < VN;
    int vc = ok ? v : VN - 1;
    int b0 = blockIdx.y * BT;

    float acc[3][BT];
#pragma unroll
    for (int c = 0; c < 3; c++)
#pragma unroll
        for (int bb = 0; bb < BT; bb++) acc[c][bb] = 0.0f;

    const float4* sp = sdpT4 + vc;   // + (c*NL4 + l4)*VP walks K; lane walks v

    // prologue: prefetch iteration 0's tiles
    float4 nA0 = sp[(size_t)(0 * NL4 + 0) * VP];
    float4 nA1 = sp[(size_t)(0 * NL4 + 1) * VP];
    float4 nB0 = sp[(size_t)(1 * NL4 + 0) * VP];
    float4 nB1 = sp[(size_t)(1 * NL4 + 1) * VP];
    float4 nC0 = sp[(size_t)(2 * NL4 + 0) * VP];
    float4 nC1 = sp[(size_t)(2 * NL4 + 1) * VP];

#pragma unroll 1
    for (int l0 = 0; l0 < NBP; l0 += 8) {
        float4 a0 = nA0, a1 = nA1, b0q = nB0, b1q = nB1, c0q = nC0, c1q = nC1;
        int i0n = (l0 + 8 < NBP) ? ((l0 + 8) >> 2) : 0;   // dummy in-bounds prefetch on last iter
        nA0 = sp[(size_t)(0 * NL4 + i0n) * VP];
        nA1 = sp[(size_t)(0 * NL4 + i0n + 1) * VP];
        nB0 = sp[(size_t)(1 * NL4 + i0n) * VP];
        nB1 = sp[(size_t)(1 * NL4 + i0n + 1) * VP];
        nC0 = sp[(size_t)(2 * NL4 + i0n) * VP];
        nC1 = sp[(size_t)(2 * NL4 + i0n + 1) * VP];

        float s0[8] = {a0.x, a0.y, a0.z, a0.w, a1.x, a1.y, a1.z, a1.w};
        float s1[8] = {b0q.x, b0q.y, b0q.z, b0q.w, b1q.x, b1q.y, b1q.z, b1q.w};
        float s2[8] = {c0q.x, c0q.y, c0q.z, c0q.w, c1q.x, c1q.y, c1q.z, c1q.w};
#pragma unroll
        for (int bb = 0; bb < BT; bb++) {
            // uniform address -> scalar loads (SGPR path, K$)
            const float* brow = betasF + (size_t)(b0 + bb) * NBP + l0;
            const float4 be0 = *(const float4*)(brow);
            const float4 be1 = *(const float4*)(brow + 4);
            float be[8] = {be0.x, be0.y, be0.z, be0.w, be1.x, be1.y, be1.z, be1.w};
#pragma unroll
            for (int k = 0; k < 8; k++) {
                acc[0][bb] += be[k] * s0[k];
                acc[1][bb] += be[k] * s1[k];
                acc[2][bb] += be[k] * s2[k];
            }
        }
    }

    if (!ok) return;

    // per-lane epilogue inputs (vector loads), spill-safe placement (round 13)
    float wj[5], pdv[9][3];
#pragma unroll
    for (int j = 0; j < 5; j++) wj[j] = lw[v * 5 + j];
#pragma unroll
    for (int k = 0; k < 9; k++)
#pragma unroll
        for (int c = 0; c < 3; c++) pdv[k][c] = pd[(size_t)(9 + k) * N3 + v * 3 + c];

#pragma unroll    // full unroll: acc must stay register-indexed
    for (int bb = 0; bb < BT; bb++) {
        int b = b0 + bb;
        const float* pf = pf9 + b * 12;   // uniform -> scalar loads
        const float* rb = rel + b * 80;   // uniform -> scalar loads
        float vp[3];
#pragma unroll
        for (int c = 0; c < 3; c++) {
            float x = acc[c][bb];                     // = v_shaped (template folded in)
#pragma unroll
            for (int k = 0; k < 9; k++) x += pf[k] * pdv[k][c];
            vp[c] = x;
        }
        float T[16];
#pragma unroll
        for (int e = 0; e < 16; e++) T[e] = 0.0f;
#pragma unroll
        for (int j = 0; j < 5; j++) {
            float w = wj[j];
            const float4 r0 = *(const float4*)(rb + j * 16 + 0);
            const float4 r1 = *(const float4*)(rb + j * 16 + 4);
            const float4 r2 = *(const float4*)(rb + j * 16 + 8);
            const float4 r3 = *(const float4*)(rb + j * 16 + 12);
            T[0]  += w * r0.x;  T[1]  += w * r0.y;  T[2]  += w * r0.z;  T[3]  += w * r0.w;
            T[4]  += w * r1.x;  T[5]  += w * r1.y;  T[6]  += w * r1.z;  T[7]  += w * r1.w;
            T[8]  += w * r2.x;  T[9]  += w * r2.y;  T[10] += w * r2.z;  T[11] += w * r2.w;
            T[12] += w * r3.x;  T[13] += w * r3.y;  T[14] += w * r3.z;  T[15] += w * r3.w;
        }
        float vo[3];
#pragma unroll
        for (int rr = 0; rr < 3; rr++)
            vo[rr] = T[rr * 4 + 0] * vp[0] + T[rr * 4 + 1] * vp[1] + T[rr * 4 + 2] * vp[2] + T[rr * 4 + 3];

        size_t vbase = (size_t)b * VN + v;
        float* pv = outv + vbase * 3;
        pv[0] = vo[0];
        pv[1] = vo[1];
        pv[2] = vo[2];
        float4* pT = (float4*)(outT + vbase * 16);
        pT[0] = make_float4(T[0],  T[1],  T[2],  T[3]);
        pT[1] = make_float4(T[4],  T[5],  T[6],  T[7]);
        pT[2] = make_float4(T[8],  T[9],  T[10], T[11]);
        pT[3] = make_float4(T[12], T[13], T[14], T[15]);
    }
}

// ---------------- launch ----------------
extern "C" void kernel_launch(void* const* d_in, const int* in_sizes, int n_in,
                              void* d_out, int out_size, void* d_ws, size_t ws_size,
                              hipStream_t stream) {
    const float* shp  = (const float*)d_in[0];  // [1024,100]
    const float* expr = (const float*)d_in[1];  // [1024,50]
    const float* pose = (const float*)d_in[2];  // [1024,6]
    const float* vt   = (const float*)d_in[3];  // [5023,3]
    const float* sd   = (const float*)d_in[4];  // [5023,3,150]
    const float* pd   = (const float*)d_in[5];  // [36,15069]
    const float* jr   = (const float*)d_in[6];  // [5,5023]
    const float* lw   = (const float*)d_in[7];  // [5023,5]

    float* outv = (float*)d_out;
    float* outT = outv + (size_t)NBATCH * VN * 3;

    char* w = (char*)d_ws;
    const size_t SDPT_B  = (size_t)3 * NL4 * VP * 16;       // 9,163,776
    const size_t JS_B    = 15 * NBP * 4;                    // 9,120
    const size_t BETAS_B = (size_t)NBATCH * NBP * 4;        // 622,592
    const size_t PF9_B   = (size_t)NBATCH * 12 * 4;         // 49,152
    float4* sdpT4 = (float4*)w;
    float* JS     = (float*)(w + SDPT_B);
    float* betasF = (float*)(w + SDPT_B + JS_B);
    float* pf9    = (float*)(w + SDPT_B + JS_B + BETAS_B);
    float* rel    = (float*)(w + SDPT_B + JS_B + BETAS_B + PF9_B);

    k0_t4<<<(3 * NL4 * VP + 255) / 256, 256, 0, stream>>>(sd, vt, sdpT4);
    k1_t4<<<dim3(15, NL4), 256, 0, stream>>>(jr, sdpT4, JS);
    k2_pose<<<NBATCH, 64, 0, stream>>>(shp, expr, pose, JS, betasF, pf9, rel);
    k3_main<<<dim3(40, NBATCH / BT), 128, 0, stream>>>(sdpT4, pd, lw, betasF, pf9, rel, outv, outT);
}